// Round 6
// baseline (367.785 us; speedup 1.0000x reference)
//
#include <hip/hip_runtime.h>
#include <math.h>

#define H    128
#define TT   128
#define CH   8            // t-group size (K2 blocks / K3 reduce granularity)
#define NCH  (TT / CH)    // 16

// ws float offsets
#define OFF_H1V   0                 // [b][t][256]  h1 | v      : 262144 floats
#define OFF_PARTS 262144            // [b][t][1024] z2 | ad     : 1048576 floats

typedef __attribute__((ext_vector_type(2))) float f2;

__device__ __forceinline__ float sigf(float x)       { return 1.0f / (1.0f + __expf(-x)); }
__device__ __forceinline__ float tanhf_fast(float x) { return 1.0f - 2.0f / (1.0f + __expf(2.0f * x)); }

// sum over the 4-lane p-group via DPP quad_perm (VALU, no LDS traffic)
__device__ __forceinline__ float quad_sum(float v) {
    int t = __builtin_amdgcn_update_dpp(0, __float_as_int(v), 0xB1, 0xF, 0xF, true); // xor 1
    v += __int_as_float(t);
    t = __builtin_amdgcn_update_dpp(0, __float_as_int(v), 0x4E, 0xF, 0xF, true);     // xor 2
    v += __int_as_float(t);
    return v;
}

// Per-step barrier: LDS-only drain (no global-store drain anywhere in-loop now).
#define BARRIER_LGKM() do { \
    asm volatile("s_waitcnt lgkmcnt(0)" ::: "memory"); \
    __builtin_amdgcn_s_barrier(); \
    asm volatile("" ::: "memory"); \
} while (0)

// Load one float4 of weights as two packed f2 pairs, pinned in arch VGPRs.
#define DECLW4(nm, src) \
    float4 _t_##nm = (src); \
    f2 nm##_a = {_t_##nm.x, _t_##nm.y}; \
    f2 nm##_b = {_t_##nm.z, _t_##nm.w}; \
    asm volatile("" : "+v"(nm##_a), "+v"(nm##_b));

// Gate-aligned weight residency: thread (rg,p) holds rows {rg,rg+128,rg+256,rg+384},
// k-slice [32p, 32p+32) -> 128 floats/thread as 64 f2 pairs.
#define LOADW_ALL(W) \
    const float4* wpa_ = (const float4*)((W) + (size_t)(rg)       * H + p * 32); \
    const float4* wpb_ = (const float4*)((W) + (size_t)(rg + 128) * H + p * 32); \
    const float4* wpc_ = (const float4*)((W) + (size_t)(rg + 256) * H + p * 32); \
    const float4* wpd_ = (const float4*)((W) + (size_t)(rg + 384) * H + p * 32); \
    DECLW4(wa0, wpa_[0]) DECLW4(wa1, wpa_[1]) DECLW4(wa2, wpa_[2]) DECLW4(wa3, wpa_[3]) \
    DECLW4(wa4, wpa_[4]) DECLW4(wa5, wpa_[5]) DECLW4(wa6, wpa_[6]) DECLW4(wa7, wpa_[7]) \
    DECLW4(wb0, wpb_[0]) DECLW4(wb1, wpb_[1]) DECLW4(wb2, wpb_[2]) DECLW4(wb3, wpb_[3]) \
    DECLW4(wb4, wpb_[4]) DECLW4(wb5, wpb_[5]) DECLW4(wb6, wpb_[6]) DECLW4(wb7, wpb_[7]) \
    DECLW4(wc0, wpc_[0]) DECLW4(wc1, wpc_[1]) DECLW4(wc2, wpc_[2]) DECLW4(wc3, wpc_[3]) \
    DECLW4(wc4, wpc_[4]) DECLW4(wc5, wpc_[5]) DECLW4(wc6, wpc_[6]) DECLW4(wc7, wpc_[7]) \
    DECLW4(wd0, wpd_[0]) DECLW4(wd1, wpd_[1]) DECLW4(wd2, wpd_[2]) DECLW4(wd3, wpd_[3]) \
    DECLW4(wd4, wpd_[4]) DECLW4(wd5, wpd_[5]) DECLW4(wd6, wpd_[6]) DECLW4(wd7, wpd_[7])

// Packed dual-FMA: acc(lo,hi) += w(lo,hi) * h(lo,hi).
#define PKFMA(acc, w, h) \
    asm("v_pk_fma_f32 %0, %1, %2, %0" : "+v"(acc) : "v"(w), "v"(h));

#define FMA1(nm, hA, hB, acc) PKFMA(acc, nm##_a, hA) PKFMA(acc, nm##_b, hB)

#define DOTJ(j) { \
    f2 hA_ = {hv##j.x, hv##j.y}; f2 hB_ = {hv##j.z, hv##j.w}; \
    FMA1(wa##j, hA_, hB_, q0) FMA1(wb##j, hA_, hB_, q1) \
    FMA1(wc##j, hA_, hB_, q2) FMA1(wd##j, hA_, hB_, q3) }

// 8 b128 broadcast reads + 64 pk_fma + quad reduction -> a0..a3 = full gate dots
#define DOT_BODY(HBASE) \
    const float4* _hp4 = (const float4*)(HBASE); \
    float4 hv0=_hp4[0],hv1=_hp4[1],hv2=_hp4[2],hv3=_hp4[3], \
           hv4=_hp4[4],hv5=_hp4[5],hv6=_hp4[6],hv7=_hp4[7]; \
    f2 q0={0.f,0.f},q1={0.f,0.f},q2={0.f,0.f},q3={0.f,0.f}; \
    DOTJ(0) DOTJ(1) DOTJ(2) DOTJ(3) DOTJ(4) DOTJ(5) DOTJ(6) DOTJ(7) \
    float a0=q0.x+q0.y, a1=q1.x+q1.y, a2=q2.x+q2.y, a3=q3.x+q3.y; \
    a0 = quad_sum(a0); a1 = quad_sum(a1); a2 = quad_sum(a2); a3 = quad_sum(a3);

// ===========================================================================
// K1: layer-1 recurrence, one block per batch (8 blocks x 512 thr).
// No flags, no atomics, no in-loop vmcnt drains — pure serial chain.
// ===========================================================================
__global__ __launch_bounds__(512)
__attribute__((amdgpu_waves_per_eu(1, 2)))
void k1_layer1(const float* __restrict__ x,
               const float* __restrict__ w_ih0,
               const float* __restrict__ w_hh0,
               const float* __restrict__ b_ih0,
               const float* __restrict__ b_hh0,
               float* __restrict__ ws) {
    const int b  = blockIdx.x;
    const int r  = threadIdx.x;
    const int rg = r >> 2, p = r & 3;
    const int wsl = rg >> 5, wpos = rg & 31;
    float* h1v = ws + OFF_H1V + (size_t)b * TT * 256;

    __shared__ float hbuf[2][144];
    __shared__ float u_s[TT];
    __shared__ float scr[512];

    LOADW_ALL(w_hh0)
    const float b0 = b_ih0[rg]       + b_hh0[rg];
    const float b1 = b_ih0[rg + 128] + b_hh0[rg + 128];
    const float b2 = b_ih0[rg + 256] + b_hh0[rg + 256];
    const float b3 = b_ih0[rg + 384] + b_hh0[rg + 384];
    const float wi0 = w_ih0[rg], wi1 = w_ih0[rg + 128];
    const float wi2 = w_ih0[rg + 256], wi3 = w_ih0[rg + 384];
    {   // u[t] = trace(x[b,t]) cooperatively (4 partials per t)
        const float* xb = x + (size_t)(b * TT + (r & 127)) * 1024;
        const int pq = r >> 7;
        float u = 0.f;
#pragma unroll
        for (int i = 0; i < 8; i++) u += xb[(pq * 8 + i) * 33];
        scr[r] = u;
    }
    if (r < 144) hbuf[0][r] = 0.f;
    __syncthreads();
    if (r < TT) u_s[r] = scr[r] + scr[r + 128] + scr[r + 256] + scr[r + 384];
    __syncthreads();

    float c1 = 0.f;
    for (int t = 0; t < TT; t++) {
        const float u = u_s[t];
        const float* hc = hbuf[t & 1];
        float* hx = hbuf[(t & 1) ^ 1];
        DOT_BODY(hc + p * 36)
        float z0 = a0 + fmaf(wi0, u, b0);
        float z1 = a1 + fmaf(wi1, u, b1);
        float z2 = a2 + fmaf(wi2, u, b2);
        float z3 = a3 + fmaf(wi3, u, b3);
        float gi = sigf(z0), gf = sigf(z1), gg = tanhf_fast(z2), go = sigf(z3);
        float di = gi * (1.f - gi) * wi0, df = gf * (1.f - gf) * wi1;
        float dg = (1.f - gg * gg) * wi2, dd = go * (1.f - go) * wi3;
        float dc = df * c1 + di * gg + gi * dg;
        c1 = gf * c1 + gi * gg;
        float th = tanhf_fast(c1);
        float hn = go * th;
        float vn = dd * th + go * (1.f - th * th) * dc;
        if (p == wsl) hx[p * 36 + wpos] = hn;           // one writer per h-index
        if (p == 0) h1v[t * 256 + rg] = hn;             // fire-and-forget
        if (p == 1) h1v[t * 256 + 128 + rg] = vn;
        BARRIER_LGKM();   // LDS-only; global stores drain at kernel end
    }
}

// ===========================================================================
// K2: w_ih1 @ (h1 | v) for all t — embarrassingly parallel.
// 128 blocks (8 b x 16 chunks) x 512 thr; each block does 8 t's, both halves.
// ===========================================================================
__global__ __launch_bounds__(512)
void k2_proj(const float* __restrict__ w_ih1, float* __restrict__ ws) {
    const int c = blockIdx.x & 15;
    const int b = blockIdx.x >> 4;
    const int r = threadIdx.x;
    const int rg = r >> 2, p = r & 3;
    const float* h1v = ws + OFF_H1V + (size_t)b * TT * 256;
    float* pbase = ws + OFF_PARTS + (size_t)b * TT * 1024;

    __shared__ float hbA[CH * 144];   // h1 slices
    __shared__ float hbB[CH * 144];   // v  slices

    LOADW_ALL(w_ih1)
    {   // stage 8 t's of h1 (threads 0..255) and v (threads 256..511)
        const int rr = r & 255;
        const int tl = rr >> 5, k4 = rr & 31, s = k4 >> 3, j = k4 & 7;
        const float* src = h1v + (size_t)(c * CH + tl) * 256 + ((r < 256) ? 0 : 128);
        float4 v = *(const float4*)(src + k4 * 4);
        float* dst = (r < 256) ? hbA : hbB;
        *(float4*)&dst[(tl * 4 + s) * 36 + j * 4] = v;
    }
    __syncthreads();
#pragma unroll
    for (int tl = 0; tl < CH; tl++) {
        {   // z-partials from h1
            DOT_BODY(hbA + (tl * 4 + p) * 36)
            float sel = (p == 0) ? a0 : (p == 1) ? a1 : (p == 2) ? a2 : a3;
            pbase[(size_t)(c * CH + tl) * 1024 + r] = sel;
        }
        {   // derivative partials from v
            DOT_BODY(hbB + (tl * 4 + p) * 36)
            float sel = (p == 0) ? a0 : (p == 1) ? a1 : (p == 2) ? a2 : a3;
            pbase[(size_t)(c * CH + tl) * 1024 + 512 + r] = sel;
        }
    }
}

// ===========================================================================
// K3: layer-2 recurrence + diag-only output scatter, one block per batch.
// ===========================================================================
__global__ __launch_bounds__(512)
__attribute__((amdgpu_waves_per_eu(1, 2)))
void k3_layer2(const float* __restrict__ w_hh1,
               const float* __restrict__ b_ih1,
               const float* __restrict__ b_hh1,
               const float* __restrict__ w_out,
               const float* __restrict__ ws,
               float* __restrict__ outp) {
    const int b  = blockIdx.x;
    const int r  = threadIdx.x;
    const int rg = r >> 2, p = r & 3;
    const int wsl = rg >> 5, wpos = rg & 31;
    const float* parts = ws + OFF_PARTS + (size_t)b * TT * 1024;

    __shared__ float hbuf[2][144];
    __shared__ float scr[512];
    __shared__ float gbuf[CH][128];

    LOADW_ALL(w_hh1)
    const float b0 = b_ih1[rg]       + b_hh1[rg];
    const float b1 = b_ih1[rg + 128] + b_hh1[rg + 128];
    const float b2 = b_ih1[rg + 256] + b_hh1[rg + 256];
    const float b3 = b_ih1[rg + 384] + b_hh1[rg + 384];
    const float wo = w_out[rg];
    if (r < 144) hbuf[0][r] = 0.f;
    __syncthreads();

    float c2 = 0.f;
    for (int c = 0; c < NCH; c++) {
#pragma unroll
        for (int tl = 0; tl < CH; tl++) {
            const int t = c * CH + tl;
            // issue partial loads FIRST; L2 latency hides under the dot
            const float* pt = parts + (size_t)t * 1024 + rg * 4;
            float4 zf = *(const float4*)pt;
            float4 af = *(const float4*)(pt + 512);
            const float* hc = hbuf[t & 1];
            float* hx = hbuf[(t & 1) ^ 1];
            DOT_BODY(hc + p * 36)
            float z0 = a0 + b0 + zf.x;
            float z1 = a1 + b1 + zf.y;
            float z2 = a2 + b2 + zf.z;
            float z3 = a3 + b3 + zf.w;
            float gi = sigf(z0), gf = sigf(z1), gg = tanhf_fast(z2), go = sigf(z3);
            float di = gi * (1.f - gi) * af.x, df = gf * (1.f - gf) * af.y;
            float dg = (1.f - gg * gg) * af.z, dd = go * (1.f - go) * af.w;
            float dc = df * c2 + di * gg + gi * dg;
            c2 = gf * c2 + gi * gg;
            float th = tanhf_fast(c2);
            if (p == wsl) hx[p * 36 + wpos] = go * th;
            float dh2 = dd * th + go * (1.f - th * th) * dc;
            if (p == 0) gbuf[tl][rg] = wo * dh2;
            BARRIER_LGKM();
        }
        // ---- reduce chunk's g and scatter ONLY the 32 diagonal scalars ----
        {
            const int w = r >> 6, l = r & 63;          // wave w handles t-local w
            float v = gbuf[w][l] + gbuf[w][l + 64];
            v = quad_sum(v);
            v += __shfl_xor(v, 4, 64);
            v += __shfl_xor(v, 8, 64);
            v += __shfl_xor(v, 16, 64);
            v += __shfl_xor(v, 32, 64);
            if (l == 0) scr[w] = v;
            BARRIER_LGKM();
            if (r < 256) {                              // 8 t x 32 diag elements
                const int tl = r >> 5, d = r & 31;
                outp[(size_t)(b * TT + c * CH + tl) * 1024 + d * 33] = scr[tl];
            }
        }
    }
}

extern "C" void kernel_launch(void* const* d_in, const int* in_sizes, int n_in,
                              void* d_out, int out_size, void* d_ws, size_t ws_size,
                              hipStream_t stream) {
    const float* x     = (const float*)d_in[0];
    const float* w_ih0 = (const float*)d_in[1];
    const float* w_hh0 = (const float*)d_in[2];
    const float* b_ih0 = (const float*)d_in[3];
    const float* b_hh0 = (const float*)d_in[4];
    const float* w_ih1 = (const float*)d_in[5];
    const float* w_hh1 = (const float*)d_in[6];
    const float* b_ih1 = (const float*)d_in[7];
    const float* b_hh1 = (const float*)d_in[8];
    const float* w_out = (const float*)d_in[9];
    // d_in[10] = b_out: constant offset, zero derivative -> unused

    float* ws = (float*)d_ws;

    // Zero the output (31/32 of it stays zero; k3 scatters diagonals).
    hipMemsetAsync(d_out, 0, (size_t)out_size, stream);

    // Serialized pipeline: stream ordering provides all cross-stage visibility
    // (no flags, no agent atomics, no in-loop vmcnt drains anywhere).
    k1_layer1<<<dim3(8),   dim3(512), 0, stream>>>(x, w_ih0, w_hh0, b_ih0, b_hh0, ws);
    k2_proj  <<<dim3(128), dim3(512), 0, stream>>>(w_ih1, ws);
    k3_layer2<<<dim3(8),   dim3(512), 0, stream>>>(w_hh1, b_ih1, b_hh1, w_out, ws,
                                                   (float*)d_out);
}

// Round 7
// 277.413 us; speedup vs baseline: 1.3258x; 1.3258x over previous
//
#include <hip/hip_runtime.h>
#include <math.h>

#define H    128
#define TT   128
#define CH   8            // steps per chunk/flag
#define NCH  (TT / CH)    // 16

// ws float offsets
#define OFF_H1V   0                 // [b][t][256]  h1 | v      : 262144 floats
#define OFF_PARTS 262144            // [b][t][1024] z2 | ad     : 1048576 floats
#define OFF_CNT   1441792           // int counters (poisoned 0xAA -> negative)

__device__ __forceinline__ float sigf(float x)       { return 1.0f / (1.0f + __expf(-x)); }
__device__ __forceinline__ float tanhf_fast(float x) { return 1.0f - 2.0f / (1.0f + __expf(2.0f * x)); }

// sum over the 4 stride-4 lanes of a row16 (p-partners in the NEW mapping):
// v + row_ror:4 + row_ror:8 covers {l, l+4, l+8, l+12} — lo-class preserved.
__device__ __forceinline__ float sum4s(float v) {
    int t = __builtin_amdgcn_update_dpp(0, __float_as_int(v), 0x124, 0xF, 0xF, true); // row_ror:4
    v += __int_as_float(t);
    t = __builtin_amdgcn_update_dpp(0, __float_as_int(v), 0x128, 0xF, 0xF, true);     // row_ror:8
    v += __int_as_float(t);
    return v;
}
// 4-lane contiguous quad sum (used only in C's chunk reduce)
__device__ __forceinline__ float quad_sum(float v) {
    int t = __builtin_amdgcn_update_dpp(0, __float_as_int(v), 0xB1, 0xF, 0xF, true);
    v += __int_as_float(t);
    t = __builtin_amdgcn_update_dpp(0, __float_as_int(v), 0x4E, 0xF, 0xF, true);
    v += __int_as_float(t);
    return v;
}

// Cheap spin: RELAXED polls, then ONE acquire load for the synchronizes-with edge.
__device__ __forceinline__ void wait_ge(int* ptr, int val) {
    while (__hip_atomic_load(ptr, __ATOMIC_RELAXED, __HIP_MEMORY_SCOPE_AGENT) < val)
        __builtin_amdgcn_s_sleep(1);
    (void)__hip_atomic_load(ptr, __ATOMIC_ACQUIRE, __HIP_MEMORY_SCOPE_AGENT);
}

// Per-step barrier: LDS-only drain (global stores stay in flight until chunk end).
#define BARRIER_LGKM() do { \
    asm volatile("s_waitcnt lgkmcnt(0)" ::: "memory"); \
    __builtin_amdgcn_s_barrier(); \
    asm volatile("" ::: "memory"); \
} while (0)

// Chunk-boundary barrier: full drain so r0's agent-scope release publishes all.
#define BARRIER_ALL() do { \
    asm volatile("s_waitcnt vmcnt(0) lgkmcnt(0)" ::: "memory"); \
    __builtin_amdgcn_s_barrier(); \
    asm volatile("" ::: "memory"); \
} while (0)

// Load one float4 of weights, pin scalars in the register file.
#define DECLW4(nm, src) \
    float4 _t_##nm = (src); \
    float nm##_x = _t_##nm.x, nm##_y = _t_##nm.y, nm##_z = _t_##nm.z, nm##_w = _t_##nm.w; \
    asm volatile("" : "+v"(nm##_x), "+v"(nm##_y), "+v"(nm##_z), "+v"(nm##_w));

// Gate-aligned weight residency: thread (rg,p) holds rows {rg,rg+128,rg+256,rg+384},
// k-slice [32p, 32p+32) -> 128 floats/thread.
#define LOADW_ALL(W) \
    const float4* wpa_ = (const float4*)((W) + (size_t)(rg)       * H + p * 32); \
    const float4* wpb_ = (const float4*)((W) + (size_t)(rg + 128) * H + p * 32); \
    const float4* wpc_ = (const float4*)((W) + (size_t)(rg + 256) * H + p * 32); \
    const float4* wpd_ = (const float4*)((W) + (size_t)(rg + 384) * H + p * 32); \
    DECLW4(wa0, wpa_[0]) DECLW4(wa1, wpa_[1]) DECLW4(wa2, wpa_[2]) DECLW4(wa3, wpa_[3]) \
    DECLW4(wa4, wpa_[4]) DECLW4(wa5, wpa_[5]) DECLW4(wa6, wpa_[6]) DECLW4(wa7, wpa_[7]) \
    DECLW4(wb0, wpb_[0]) DECLW4(wb1, wpb_[1]) DECLW4(wb2, wpb_[2]) DECLW4(wb3, wpb_[3]) \
    DECLW4(wb4, wpb_[4]) DECLW4(wb5, wpb_[5]) DECLW4(wb6, wpb_[6]) DECLW4(wb7, wpb_[7]) \
    DECLW4(wc0, wpc_[0]) DECLW4(wc1, wpc_[1]) DECLW4(wc2, wpc_[2]) DECLW4(wc3, wpc_[3]) \
    DECLW4(wc4, wpc_[4]) DECLW4(wc5, wpc_[5]) DECLW4(wc6, wpc_[6]) DECLW4(wc7, wpc_[7]) \
    DECLW4(wd0, wpd_[0]) DECLW4(wd1, wpd_[1]) DECLW4(wd2, wpd_[2]) DECLW4(wd3, wpd_[3]) \
    DECLW4(wd4, wpd_[4]) DECLW4(wd5, wpd_[5]) DECLW4(wd6, wpd_[6]) DECLW4(wd7, wpd_[7])

// quad_perm broadcast of lane q's value to the whole quad (ctrl = q * 0x55)
#define QB(dst, src, ctrl) \
    dst = __int_as_float(__builtin_amdgcn_update_dpp(0, __float_as_int(src), ctrl, 0xF, 0xF, true));

#define FMAQ(g, A, B, acc) \
    acc = fmaf(g##A##_x, h0_, acc); acc = fmaf(g##A##_y, h1_, acc); \
    acc = fmaf(g##A##_z, h2_, acc); acc = fmaf(g##A##_w, h3_, acc); \
    acc = fmaf(g##B##_x, h4_, acc); acc = fmaf(g##B##_y, h5_, acc); \
    acc = fmaf(g##B##_z, h6_, acc); acc = fmaf(g##B##_w, h7_, acc);

// Quarter q: broadcast holder-lane (lo==q)'s 8 h floats to the quad, then
// 32 FMA against weight regs 8q..8q+7 of each gate.
#define QUARTER(A, B, ctrl) { \
    float h0_, h1_, h2_, h3_, h4_, h5_, h6_, h7_; \
    QB(h0_, hA_.x, ctrl) QB(h1_, hA_.y, ctrl) QB(h2_, hA_.z, ctrl) QB(h3_, hA_.w, ctrl) \
    QB(h4_, hB_.x, ctrl) QB(h5_, hB_.y, ctrl) QB(h6_, hB_.z, ctrl) QB(h7_, hB_.w, ctrl) \
    FMAQ(wa, A, B, a0) FMAQ(wb, A, B, a1) FMAQ(wc, A, B, a2) FMAQ(wd, A, B, a3) }

// NEW DOT: each lane reads only its 8-float quarter (2 x ds_read_b128,
// 16 KB/step/CU instead of 64 KB), quad_perm DPP broadcasts the rest.
// HB = base of the 144-float h snapshot (slice p at +36p, quarter lo at +8lo).
#define DOT_BODY(HB) \
    const float4* _hq = (const float4*)((HB) + p * 36 + lo * 8); \
    float4 hA_ = _hq[0], hB_ = _hq[1]; \
    float a0 = 0.f, a1 = 0.f, a2 = 0.f, a3 = 0.f; \
    QUARTER(0, 1, 0x00) QUARTER(2, 3, 0x55) QUARTER(4, 5, 0xAA) QUARTER(6, 7, 0xFF) \
    a0 = sum4s(a0); a1 = sum4s(a1); a2 = sum4s(a2); a3 = sum4s(a3);

// ---------------------------------------------------------------------------
// Overlapped 4-role pipeline, one CU per (role,batch): 32 blocks x 512 thr.
// Lane mapping: p = (r>>2)&3 (k-slice), rg = (r&3) | ((r>>4)<<2), lo = r&3.
//   -> a quad shares p (same k-slice) with 4 consecutive rg: cooperative
//      quarter-reads + quad_perm broadcast; p-reduce partners at stride 4.
// ---------------------------------------------------------------------------
__global__ __launch_bounds__(512)
__attribute__((amdgpu_waves_per_eu(1, 2)))
void pipe_kernel(const float* __restrict__ x,
                 const float* __restrict__ w_ih0,
                 const float* __restrict__ w_hh0,
                 const float* __restrict__ b_ih0,
                 const float* __restrict__ b_hh0,
                 const float* __restrict__ w_ih1,
                 const float* __restrict__ w_hh1,
                 const float* __restrict__ b_ih1,
                 const float* __restrict__ b_hh1,
                 const float* __restrict__ w_out,
                 float* __restrict__ ws,
                 float* __restrict__ outp) {
    const int role = blockIdx.x >> 3;
    const int b    = blockIdx.x & 7;
    const int r    = threadIdx.x;
    const int p    = (r >> 2) & 3;
    const int lo   = r & 3;
    const int rg   = lo | ((r >> 4) << 2);
    const int wsl  = rg >> 5, wpos = rg & 31;

    int* cntA  = (int*)ws + OFF_CNT       + b * 32;
    int* cntB1 = (int*)ws + OFF_CNT + 256 + b * 32;
    int* cntB2 = (int*)ws + OFF_CNT + 512 + b * 32;
    float* h1v = ws + OFF_H1V + (size_t)b * TT * 256;

    __shared__ __align__(16) float hbuf[2][144];    // 4 padded slices x 36
    __shared__ float u_s[TT];
    __shared__ float scr[512];
    __shared__ __align__(16) float hb[CH * 144];    // B chunk staging
    __shared__ float gbuf[CH][128];                 // C: per-chunk unreduced g

    if (role == 0) {
        // ===================== Stage A: layer-1 recurrence =====================
        LOADW_ALL(w_hh0)
        const float b0 = b_ih0[rg]       + b_hh0[rg];
        const float b1 = b_ih0[rg + 128] + b_hh0[rg + 128];
        const float b2 = b_ih0[rg + 256] + b_hh0[rg + 256];
        const float b3 = b_ih0[rg + 384] + b_hh0[rg + 384];
        const float wi0 = w_ih0[rg], wi1 = w_ih0[rg + 128];
        const float wi2 = w_ih0[rg + 256], wi3 = w_ih0[rg + 384];
        {   // u[t] = trace(x[b,t]) cooperatively (4 partials per t)
            const float* xb = x + (size_t)(b * TT + (r & 127)) * 1024;
            const int pq = r >> 7;
            float u = 0.f;
#pragma unroll
            for (int i = 0; i < 8; i++) u += xb[(pq * 8 + i) * 33];
            scr[r] = u;
        }
        if (r < 144) hbuf[0][r] = 0.f;
        __syncthreads();
        if (r < TT) u_s[r] = scr[r] + scr[r + 128] + scr[r + 256] + scr[r + 384];
        __syncthreads();

        float c1 = 0.f;
        float hn_prev = 0.f, vn_prev = 0.f;
        for (int t = 0; t < TT; t++) {
            // publish PREVIOUS step's h1v early (issues during this step's work)
            if (t & (CH - 1)) {
                if (p == 0) h1v[(t - 1) * 256 + rg] = hn_prev;
                if (p == 1) h1v[(t - 1) * 256 + 128 + rg] = vn_prev;
            }
            const float u = u_s[t];
            const float* hc = hbuf[t & 1];
            float* hx = hbuf[(t & 1) ^ 1];
            DOT_BODY(hc)
            float z0 = a0 + fmaf(wi0, u, b0);
            float z1 = a1 + fmaf(wi1, u, b1);
            float z2 = a2 + fmaf(wi2, u, b2);
            float z3 = a3 + fmaf(wi3, u, b3);
            float gi = sigf(z0), gf = sigf(z1), gg = tanhf_fast(z2), go = sigf(z3);
            float di = gi * (1.f - gi) * wi0, df = gf * (1.f - gf) * wi1;
            float dg = (1.f - gg * gg) * wi2, dd = go * (1.f - go) * wi3;
            float dc = df * c1 + di * gg + gi * dg;
            c1 = gf * c1 + gi * gg;
            float th = tanhf_fast(c1);
            float hn = go * th;
            float vn = dd * th + go * (1.f - th * th) * dc;
            if (p == wsl) hx[wsl * 36 + wpos] = hn;     // one writer per h-index
            if ((t & (CH - 1)) == CH - 1) {
                if (p == 0) h1v[t * 256 + rg] = hn;     // chunk end: publish NOW
                if (p == 1) h1v[t * 256 + 128 + rg] = vn;
                BARRIER_ALL();   // drain chunk's global stores before the flag
                if (r == 0)
                    __hip_atomic_store(cntA, t + 1, __ATOMIC_RELEASE, __HIP_MEMORY_SCOPE_AGENT);
            } else {
                hn_prev = hn; vn_prev = vn;
                BARRIER_LGKM();  // LDS recurrence state only — no vmcnt drain
            }
        }
    } else if (role == 1 || role == 2) {
        // ============ Stages B1/B2: w_ih1 @ (h1 | v), chunk-parallel ============
        LOADW_ALL(w_ih1)
        int* myCnt = (role == 2) ? cntB2 : cntB1;
        const float* hsrc = h1v + ((role == 2) ? 128 : 0);
        float* pbase = ws + OFF_PARTS + (size_t)b * TT * 1024 + ((role == 2) ? 512 : 0);
        const int sidx = (rg << 2) | p;   // gate-p of rg -> C reads float4 at rg*4
        for (int c = 0; c < NCH; c++) {
            if (r == 0) wait_ge(cntA, (c + 1) * CH);
            __syncthreads();
            if (r < 256) {   // stage chunk into padded slices
                int tl = r >> 5, k4 = r & 31, s = k4 >> 3, j = k4 & 7;
                float4 v = *(const float4*)(hsrc + (size_t)(c * CH + tl) * 256 + k4 * 4);
                *(float4*)&hb[(tl * 4 + s) * 36 + j * 4] = v;
            }
            __syncthreads();
#pragma unroll
            for (int tl = 0; tl < CH; tl++) {
                DOT_BODY(hb + tl * 144)
                float sel = (p == 0) ? a0 : (p == 1) ? a1 : (p == 2) ? a2 : a3;
                pbase[(size_t)(c * CH + tl) * 1024 + sidx] = sel;
            }
            BARRIER_ALL();   // drain all chunk stores before flag
            if (r == 0)
                __hip_atomic_store(myCnt, (c + 1) * CH, __ATOMIC_RELEASE, __HIP_MEMORY_SCOPE_AGENT);
        }
    } else {
        // ==== Stage C: w_hh1 @ h2 + layer-2 elementwise + diag-only scatter ====
        LOADW_ALL(w_hh1)
        const float b0 = b_ih1[rg]       + b_hh1[rg];
        const float b1 = b_ih1[rg + 128] + b_hh1[rg + 128];
        const float b2 = b_ih1[rg + 256] + b_hh1[rg + 256];
        const float b3 = b_ih1[rg + 384] + b_hh1[rg + 384];
        const float wo = w_out[rg];
        if (r < 144) hbuf[0][r] = 0.f;
        __syncthreads();
        const float* parts = ws + OFF_PARTS + (size_t)b * TT * 1024;
        float c2 = 0.f;
        for (int c = 0; c < NCH; c++) {
            if (r == 0) { wait_ge(cntB1, (c + 1) * CH); wait_ge(cntB2, (c + 1) * CH); }
            __syncthreads();
#pragma unroll
            for (int tl = 0; tl < CH; tl++) {
                const int t = c * CH + tl;
                // issue partial loads FIRST; L2 latency hides under the dot
                const float* pt = parts + (size_t)t * 1024 + rg * 4;
                float4 zf = *(const float4*)pt;
                float4 af = *(const float4*)(pt + 512);
                const float* hc = hbuf[t & 1];
                float* hx = hbuf[(t & 1) ^ 1];
                DOT_BODY(hc)
                float z0 = a0 + b0 + zf.x;
                float z1 = a1 + b1 + zf.y;
                float z2 = a2 + b2 + zf.z;
                float z3 = a3 + b3 + zf.w;
                float gi = sigf(z0), gf = sigf(z1), gg = tanhf_fast(z2), go = sigf(z3);
                float di = gi * (1.f - gi) * af.x, df = gf * (1.f - gf) * af.y;
                float dg = (1.f - gg * gg) * af.z, dd = go * (1.f - go) * af.w;
                float dc = df * c2 + di * gg + gi * dg;
                c2 = gf * c2 + gi * gg;
                float th = tanhf_fast(c2);
                if (p == wsl) hx[wsl * 36 + wpos] = go * th;
                float dh2 = dd * th + go * (1.f - th * th) * dc;
                if (p == 0) gbuf[tl][rg] = wo * dh2;   // unreduced, LDS
                BARRIER_LGKM();   // hbuf + gbuf are LDS-only -> no vmcnt drain
            }
            // ---- reduce chunk's g and scatter ONLY the 32 diagonal scalars ----
            {
                const int w = r >> 6, l = r & 63;      // wave w handles t-local w
                float v = gbuf[w][l] + gbuf[w][l + 64];
                v = quad_sum(v);
                v += __shfl_xor(v, 4, 64);
                v += __shfl_xor(v, 8, 64);
                v += __shfl_xor(v, 16, 64);
                v += __shfl_xor(v, 32, 64);
                if (l == 0) scr[w] = v;
                BARRIER_LGKM();
                if (r < 256) {                          // 8 t x 32 diag elements
                    const int tl = r >> 5, d = r & 31;
                    outp[(size_t)(b * TT + c * CH + tl) * 1024 + d * 33] = scr[tl];
                }
            }
        }
    }
}

extern "C" void kernel_launch(void* const* d_in, const int* in_sizes, int n_in,
                              void* d_out, int out_size, void* d_ws, size_t ws_size,
                              hipStream_t stream) {
    const float* x     = (const float*)d_in[0];
    const float* w_ih0 = (const float*)d_in[1];
    const float* w_hh0 = (const float*)d_in[2];
    const float* b_ih0 = (const float*)d_in[3];
    const float* b_hh0 = (const float*)d_in[4];
    const float* w_ih1 = (const float*)d_in[5];
    const float* w_hh1 = (const float*)d_in[6];
    const float* b_ih1 = (const float*)d_in[7];
    const float* b_hh1 = (const float*)d_in[8];
    const float* w_out = (const float*)d_in[9];
    // d_in[10] = b_out: constant offset, zero derivative -> unused

    float* ws = (float*)d_ws;   // counters rely on 0xAA poison (<0 as int)

    // Zero the output (31/32 of it stays zero; pipe_kernel scatters diagonals).
    hipMemsetAsync(d_out, 0, (size_t)out_size, stream);

    pipe_kernel<<<dim3(32), dim3(512), 0, stream>>>(x, w_ih0, w_hh0, b_ih0, b_hh0,
                                                    w_ih1, w_hh1, b_ih1, b_hh1, w_out,
                                                    ws, (float*)d_out);
}

// Round 8
// 253.830 us; speedup vs baseline: 1.4489x; 1.0929x over previous
//
#include <hip/hip_runtime.h>
#include <math.h>

#define H    128
#define TT   128
#define CH   4            // steps per chunk/flag (was 8: shorter fill/drain)
#define NCH  (TT / CH)    // 32

// ws float offsets
#define OFF_H1V   0                 // [b][t][256]  h1 | v      : 262144 floats
#define OFF_PARTS 262144            // [b][t][1024] z2 | ad     : 1048576 floats
#define OFF_CNT   1441792           // int counters (poisoned 0xAA -> negative)

typedef __attribute__((ext_vector_type(2))) float f2;

__device__ __forceinline__ float sigf(float x)       { return 1.0f / (1.0f + __expf(-x)); }
__device__ __forceinline__ float tanhf_fast(float x) { return 1.0f - 2.0f / (1.0f + __expf(2.0f * x)); }

// sum over the 4-lane p-group via DPP quad_perm (VALU, no LDS traffic)
__device__ __forceinline__ float quad_sum(float v) {
    int t = __builtin_amdgcn_update_dpp(0, __float_as_int(v), 0xB1, 0xF, 0xF, true); // xor 1
    v += __int_as_float(t);
    t = __builtin_amdgcn_update_dpp(0, __float_as_int(v), 0x4E, 0xF, 0xF, true);     // xor 2
    v += __int_as_float(t);
    return v;
}

// Cheap spin: RELAXED polls, then ONE acquire load for the synchronizes-with edge.
__device__ __forceinline__ void wait_ge(int* ptr, int val) {
    while (__hip_atomic_load(ptr, __ATOMIC_RELAXED, __HIP_MEMORY_SCOPE_AGENT) < val)
        __builtin_amdgcn_s_sleep(1);
    (void)__hip_atomic_load(ptr, __ATOMIC_ACQUIRE, __HIP_MEMORY_SCOPE_AGENT);
}

// Per-step barrier: LDS-only drain (global stores stay in flight until chunk end).
#define BARRIER_LGKM() do { \
    asm volatile("s_waitcnt lgkmcnt(0)" ::: "memory"); \
    __builtin_amdgcn_s_barrier(); \
    asm volatile("" ::: "memory"); \
} while (0)

// Chunk-boundary barrier: full drain so r0's agent-scope release publishes all.
#define BARRIER_ALL() do { \
    asm volatile("s_waitcnt vmcnt(0) lgkmcnt(0)" ::: "memory"); \
    __builtin_amdgcn_s_barrier(); \
    asm volatile("" ::: "memory"); \
} while (0)

// Load one float4 of weights as two packed f2 pairs, pinned in the reg file.
#define DECLW4(nm, src) \
    float4 _t_##nm = (src); \
    f2 nm##_a = {_t_##nm.x, _t_##nm.y}; \
    f2 nm##_b = {_t_##nm.z, _t_##nm.w}; \
    asm volatile("" : "+v"(nm##_a), "+v"(nm##_b));

// Gate-aligned weight residency: thread (rg,p) holds rows {rg,rg+128,rg+256,rg+384},
// k-slice [32p, 32p+32) -> 128 floats/thread as 64 f2 pairs.
#define LOADW_ALL(W) \
    const float4* wpa_ = (const float4*)((W) + (size_t)(rg)       * H + p * 32); \
    const float4* wpb_ = (const float4*)((W) + (size_t)(rg + 128) * H + p * 32); \
    const float4* wpc_ = (const float4*)((W) + (size_t)(rg + 256) * H + p * 32); \
    const float4* wpd_ = (const float4*)((W) + (size_t)(rg + 384) * H + p * 32); \
    DECLW4(wa0, wpa_[0]) DECLW4(wa1, wpa_[1]) DECLW4(wa2, wpa_[2]) DECLW4(wa3, wpa_[3]) \
    DECLW4(wa4, wpa_[4]) DECLW4(wa5, wpa_[5]) DECLW4(wa6, wpa_[6]) DECLW4(wa7, wpa_[7]) \
    DECLW4(wb0, wpb_[0]) DECLW4(wb1, wpb_[1]) DECLW4(wb2, wpb_[2]) DECLW4(wb3, wpb_[3]) \
    DECLW4(wb4, wpb_[4]) DECLW4(wb5, wpb_[5]) DECLW4(wb6, wpb_[6]) DECLW4(wb7, wpb_[7]) \
    DECLW4(wc0, wpc_[0]) DECLW4(wc1, wpc_[1]) DECLW4(wc2, wpc_[2]) DECLW4(wc3, wpc_[3]) \
    DECLW4(wc4, wpc_[4]) DECLW4(wc5, wpc_[5]) DECLW4(wc6, wpc_[6]) DECLW4(wc7, wpc_[7]) \
    DECLW4(wd0, wpd_[0]) DECLW4(wd1, wpd_[1]) DECLW4(wd2, wpd_[2]) DECLW4(wd3, wpd_[3]) \
    DECLW4(wd4, wpd_[4]) DECLW4(wd5, wpd_[5]) DECLW4(wd6, wpd_[6]) DECLW4(wd7, wpd_[7])

// Packed dual-FMA: acc(lo,hi) += w(lo,hi) * h(lo,hi).
#define PKFMA(acc, w, h) \
    asm("v_pk_fma_f32 %0, %1, %2, %0" : "+v"(acc) : "v"(w), "v"(h));

#define FMA1(nm, hA, hB, acc) PKFMA(acc, nm##_a, hA) PKFMA(acc, nm##_b, hB)

#define DOTJ(j, Q0, Q1, Q2, Q3) { \
    f2 hA_ = {hv##j.x, hv##j.y}; f2 hB_ = {hv##j.z, hv##j.w}; \
    FMA1(wa##j, hA_, hB_, Q0) FMA1(wb##j, hA_, hB_, Q1) \
    FMA1(wc##j, hA_, hB_, Q2) FMA1(wd##j, hA_, hB_, Q3) }

// 8 b128 broadcast reads + 64 pk_fma in TWO independent 8-deep chains per gate
// (halves the dependent-FMA latency on the step's serial path) + quad reduce.
#define DOT_BODY(HBASE) \
    const float4* _hp4 = (const float4*)(HBASE); \
    float4 hv0=_hp4[0],hv1=_hp4[1],hv2=_hp4[2],hv3=_hp4[3], \
           hv4=_hp4[4],hv5=_hp4[5],hv6=_hp4[6],hv7=_hp4[7]; \
    f2 q0={0.f,0.f},q1={0.f,0.f},q2={0.f,0.f},q3={0.f,0.f}; \
    f2 s0={0.f,0.f},s1={0.f,0.f},s2={0.f,0.f},s3={0.f,0.f}; \
    DOTJ(0,q0,q1,q2,q3) DOTJ(1,s0,s1,s2,s3) \
    DOTJ(2,q0,q1,q2,q3) DOTJ(3,s0,s1,s2,s3) \
    DOTJ(4,q0,q1,q2,q3) DOTJ(5,s0,s1,s2,s3) \
    DOTJ(6,q0,q1,q2,q3) DOTJ(7,s0,s1,s2,s3) \
    float a0=(q0.x+q0.y)+(s0.x+s0.y), a1=(q1.x+q1.y)+(s1.x+s1.y), \
          a2=(q2.x+q2.y)+(s2.x+s2.y), a3=(q3.x+q3.y)+(s3.x+s3.y); \
    a0 = quad_sum(a0); a1 = quad_sum(a1); a2 = quad_sum(a2); a3 = quad_sum(a3);

// ---------------------------------------------------------------------------
// Overlapped 4-role pipeline, one CU per (role,batch): 32 blocks x 512 thr.
//   role 0 = A : layer-1 recurrence (w_hh0)        -> h1[t], v[t]
//   role 1 = B1: w_ih1 @ h1 (chunked)              -> parts[.., 0:512)
//   role 2 = B2: w_ih1 @ v  (chunked)              -> parts[.., 512:1024)
//   role 3 = C : w_hh1 @ h2 + elementwise -> DIAGONAL-only output scatter
// Output zeros are pre-written by hipMemsetAsync before this kernel.
// CH=4: pipeline fill/drain = 2*CH = 8 steps (was 16) — critical path
// 128+8 = 136 steps; extra per-chunk flag cost ~400cy is the trade.
// ---------------------------------------------------------------------------
__global__ __launch_bounds__(512)
__attribute__((amdgpu_waves_per_eu(1, 2)))
void pipe_kernel(const float* __restrict__ x,
                 const float* __restrict__ w_ih0,
                 const float* __restrict__ w_hh0,
                 const float* __restrict__ b_ih0,
                 const float* __restrict__ b_hh0,
                 const float* __restrict__ w_ih1,
                 const float* __restrict__ w_hh1,
                 const float* __restrict__ b_ih1,
                 const float* __restrict__ b_hh1,
                 const float* __restrict__ w_out,
                 float* __restrict__ ws,
                 float* __restrict__ outp) {
    const int role = blockIdx.x >> 3;
    const int b    = blockIdx.x & 7;
    const int r    = threadIdx.x;
    const int rg   = r >> 2, p = r & 3;
    const int wsl  = rg >> 5, wpos = rg & 31;

    int* cntA  = (int*)ws + OFF_CNT       + b * 32;
    int* cntB1 = (int*)ws + OFF_CNT + 256 + b * 32;
    int* cntB2 = (int*)ws + OFF_CNT + 512 + b * 32;
    float* h1v = ws + OFF_H1V + (size_t)b * TT * 256;

    __shared__ float hbuf[2][144];    // recurrent state, 4 padded slices x 36
    __shared__ float u_s[TT];
    __shared__ float scr[512];
    __shared__ float hb[CH * 144];    // B chunk staging
    __shared__ float gbuf[CH][128];   // C: per-chunk unreduced g

    if (role == 0) {
        // ===================== Stage A: layer-1 recurrence =====================
        LOADW_ALL(w_hh0)
        const float b0 = b_ih0[rg]       + b_hh0[rg];
        const float b1 = b_ih0[rg + 128] + b_hh0[rg + 128];
        const float b2 = b_ih0[rg + 256] + b_hh0[rg + 256];
        const float b3 = b_ih0[rg + 384] + b_hh0[rg + 384];
        const float wi0 = w_ih0[rg], wi1 = w_ih0[rg + 128];
        const float wi2 = w_ih0[rg + 256], wi3 = w_ih0[rg + 384];
        {   // u[t] = trace(x[b,t]) cooperatively (4 partials per t)
            const float* xb = x + (size_t)(b * TT + (r & 127)) * 1024;
            const int pq = r >> 7;
            float u = 0.f;
#pragma unroll
            for (int i = 0; i < 8; i++) u += xb[(pq * 8 + i) * 33];
            scr[r] = u;
        }
        if (r < 144) hbuf[0][r] = 0.f;
        __syncthreads();
        if (r < TT) u_s[r] = scr[r] + scr[r + 128] + scr[r + 256] + scr[r + 384];
        __syncthreads();

        float c1 = 0.f;
        float hn_prev = 0.f, vn_prev = 0.f;
        for (int t = 0; t < TT; t++) {
            // publish PREVIOUS step's h1v early (issues during this step's work)
            if (t & (CH - 1)) {
                if (p == 0) h1v[(t - 1) * 256 + rg] = hn_prev;
                if (p == 1) h1v[(t - 1) * 256 + 128 + rg] = vn_prev;
            }
            const float u = u_s[t];
            const float* hc = hbuf[t & 1];
            float* hx = hbuf[(t & 1) ^ 1];
            DOT_BODY(hc + p * 36)
            float z0 = a0 + fmaf(wi0, u, b0);
            float z1 = a1 + fmaf(wi1, u, b1);
            float z2 = a2 + fmaf(wi2, u, b2);
            float z3 = a3 + fmaf(wi3, u, b3);
            float gi = sigf(z0), gf = sigf(z1), gg = tanhf_fast(z2), go = sigf(z3);
            float di = gi * (1.f - gi) * wi0, df = gf * (1.f - gf) * wi1;
            float dg = (1.f - gg * gg) * wi2, dd = go * (1.f - go) * wi3;
            float dc = df * c1 + di * gg + gi * dg;
            c1 = gf * c1 + gi * gg;
            float th = tanhf_fast(c1);
            float hn = go * th;
            float vn = dd * th + go * (1.f - th * th) * dc;
            if (p == wsl) hx[p * 36 + wpos] = hn;       // one writer per h-index
            if ((t & (CH - 1)) == CH - 1) {
                if (p == 0) h1v[t * 256 + rg] = hn;     // chunk end: publish NOW
                if (p == 1) h1v[t * 256 + 128 + rg] = vn;
                BARRIER_ALL();   // drain chunk's global stores before the flag
                if (r == 0)
                    __hip_atomic_store(cntA, t + 1, __ATOMIC_RELEASE, __HIP_MEMORY_SCOPE_AGENT);
            } else {
                hn_prev = hn; vn_prev = vn;
                BARRIER_LGKM();  // LDS recurrence state only — no vmcnt drain
            }
        }
    } else if (role == 1 || role == 2) {
        // ============ Stages B1/B2: w_ih1 @ (h1 | v), chunk-parallel ============
        LOADW_ALL(w_ih1)
        int* myCnt = (role == 2) ? cntB2 : cntB1;
        const float* hsrc = h1v + ((role == 2) ? 128 : 0);
        float* pbase = ws + OFF_PARTS + (size_t)b * TT * 1024 + ((role == 2) ? 512 : 0);
        for (int c = 0; c < NCH; c++) {
            if (r == 0) wait_ge(cntA, (c + 1) * CH);
            __syncthreads();
            if (r < CH * 32) {   // stage chunk into padded slices (CH t x 32 f4)
                int tl = r >> 5, k4 = r & 31, s = k4 >> 3, j = k4 & 7;
                float4 v = *(const float4*)(hsrc + (size_t)(c * CH + tl) * 256 + k4 * 4);
                *(float4*)&hb[(tl * 4 + s) * 36 + j * 4] = v;
            }
            __syncthreads();
#pragma unroll
            for (int tl = 0; tl < CH; tl++) {
                DOT_BODY(hb + (tl * 4 + p) * 36)
                // lane p stores gate-p's dot -> C reads 4 gates back as ONE float4
                float sel = (p == 0) ? a0 : (p == 1) ? a1 : (p == 2) ? a2 : a3;
                pbase[(size_t)(c * CH + tl) * 1024 + r] = sel;
            }
            BARRIER_ALL();   // drain all chunk stores before flag
            if (r == 0)
                __hip_atomic_store(myCnt, (c + 1) * CH, __ATOMIC_RELEASE, __HIP_MEMORY_SCOPE_AGENT);
        }
    } else {
        // ==== Stage C: w_hh1 @ h2 + layer-2 elementwise + diag-only scatter ====
        LOADW_ALL(w_hh1)
        const float b0 = b_ih1[rg]       + b_hh1[rg];
        const float b1 = b_ih1[rg + 128] + b_hh1[rg + 128];
        const float b2 = b_ih1[rg + 256] + b_hh1[rg + 256];
        const float b3 = b_ih1[rg + 384] + b_hh1[rg + 384];
        const float wo = w_out[rg];
        if (r < 144) hbuf[0][r] = 0.f;
        __syncthreads();
        const float* parts = ws + OFF_PARTS + (size_t)b * TT * 1024;
        float c2 = 0.f;
        for (int c = 0; c < NCH; c++) {
            if (r == 0) { wait_ge(cntB1, (c + 1) * CH); wait_ge(cntB2, (c + 1) * CH); }
            __syncthreads();
            float4 zf[CH], af[CH];   // prefetch whole chunk's partials (hide L2 lat)
#pragma unroll
            for (int tl = 0; tl < CH; tl++) {
                zf[tl] = *(const float4*)(parts + (size_t)(c * CH + tl) * 1024 + rg * 4);
                af[tl] = *(const float4*)(parts + (size_t)(c * CH + tl) * 1024 + 512 + rg * 4);
            }
#pragma unroll
            for (int tl = 0; tl < CH; tl++) {
                const int t = c * CH + tl;
                const float* hc = hbuf[t & 1];
                float* hx = hbuf[(t & 1) ^ 1];
                DOT_BODY(hc + p * 36)
                float z0 = a0 + b0 + zf[tl].x;
                float z1 = a1 + b1 + zf[tl].y;
                float z2 = a2 + b2 + zf[tl].z;
                float z3 = a3 + b3 + zf[tl].w;
                float gi = sigf(z0), gf = sigf(z1), gg = tanhf_fast(z2), go = sigf(z3);
                float di = gi * (1.f - gi) * af[tl].x, df = gf * (1.f - gf) * af[tl].y;
                float dg = (1.f - gg * gg) * af[tl].z, dd = go * (1.f - go) * af[tl].w;
                float dc = df * c2 + di * gg + gi * dg;
                c2 = gf * c2 + gi * gg;
                float th = tanhf_fast(c2);
                if (p == wsl) hx[p * 36 + wpos] = go * th;
                float dh2 = dd * th + go * (1.f - th * th) * dc;
                if (p == 0) gbuf[tl][rg] = wo * dh2;   // unreduced, LDS
                BARRIER_LGKM();   // hbuf + gbuf are LDS-only -> no vmcnt drain
            }
            // ---- reduce chunk's g and scatter ONLY the 32 diagonal scalars ----
            {
                const int w = r >> 6, l = r & 63;      // wave w handles t-local w
                if (w < CH) {
                    float v = gbuf[w][l] + gbuf[w][l + 64];
                    v = quad_sum(v);
                    v += __shfl_xor(v, 4, 64);
                    v += __shfl_xor(v, 8, 64);
                    v += __shfl_xor(v, 16, 64);
                    v += __shfl_xor(v, 32, 64);
                    if (l == 0) scr[w] = v;
                }
                BARRIER_LGKM();
                if (r < CH * 32) {                      // CH t x 32 diag elements
                    const int tl = r >> 5, d = r & 31;
                    outp[(size_t)(b * TT + c * CH + tl) * 1024 + d * 33] = scr[tl];
                }
            }
        }
    }
}

extern "C" void kernel_launch(void* const* d_in, const int* in_sizes, int n_in,
                              void* d_out, int out_size, void* d_ws, size_t ws_size,
                              hipStream_t stream) {
    const float* x     = (const float*)d_in[0];
    const float* w_ih0 = (const float*)d_in[1];
    const float* w_hh0 = (const float*)d_in[2];
    const float* b_ih0 = (const float*)d_in[3];
    const float* b_hh0 = (const float*)d_in[4];
    const float* w_ih1 = (const float*)d_in[5];
    const float* w_hh1 = (const float*)d_in[6];
    const float* b_ih1 = (const float*)d_in[7];
    const float* b_hh1 = (const float*)d_in[8];
    const float* w_out = (const float*)d_in[9];
    // d_in[10] = b_out: constant offset, zero derivative -> unused

    float* ws = (float*)d_ws;   // counters rely on 0xAA poison (<0 as int)

    // Zero the output (31/32 of it stays zero; pipe_kernel scatters diagonals).
    hipMemsetAsync(d_out, 0, (size_t)out_size, stream);

    pipe_kernel<<<dim3(32), dim3(512), 0, stream>>>(x, w_ih0, w_hh0, b_ih0, b_hh0,
                                                    w_ih1, w_hh1, b_ih1, b_hh1, w_out,
                                                    ws, (float*)d_out);
}

// Round 9
// 235.304 us; speedup vs baseline: 1.5630x; 1.0787x over previous
//
#include <hip/hip_runtime.h>
#include <math.h>

#define H    128
#define TT   128
#define CH   8            // steps per chunk/flag
#define NCH  (TT / CH)    // 16

// ws float offsets
#define OFF_H1V   0                 // [b][t][256]  h1 | v      : 262144 floats
#define OFF_PARTS 262144            // [b][t][1024] z2 | ad     : 1048576 floats
#define OFF_CNT   1441792           // int counters (poisoned 0xAA -> negative)

typedef __attribute__((ext_vector_type(2))) float f2;

__device__ __forceinline__ float sigf(float x)       { return 1.0f / (1.0f + __expf(-x)); }
__device__ __forceinline__ float tanhf_fast(float x) { return 1.0f - 2.0f / (1.0f + __expf(2.0f * x)); }

// sum over the 4-lane p-group via DPP quad_perm (VALU, no LDS traffic)
__device__ __forceinline__ float quad_sum(float v) {
    int t = __builtin_amdgcn_update_dpp(0, __float_as_int(v), 0xB1, 0xF, 0xF, true); // xor 1
    v += __int_as_float(t);
    t = __builtin_amdgcn_update_dpp(0, __float_as_int(v), 0x4E, 0xF, 0xF, true);     // xor 2
    v += __int_as_float(t);
    return v;
}

// Cheap spin: RELAXED polls, then ONE acquire load for the synchronizes-with edge.
__device__ __forceinline__ void wait_ge(int* ptr, int val) {
    while (__hip_atomic_load(ptr, __ATOMIC_RELAXED, __HIP_MEMORY_SCOPE_AGENT) < val)
        __builtin_amdgcn_s_sleep(1);
    (void)__hip_atomic_load(ptr, __ATOMIC_ACQUIRE, __HIP_MEMORY_SCOPE_AGENT);
}

// Per-step barrier: LDS-only drain (global stores stay in flight until chunk end).
#define BARRIER_LGKM() do { \
    asm volatile("s_waitcnt lgkmcnt(0)" ::: "memory"); \
    __builtin_amdgcn_s_barrier(); \
    asm volatile("" ::: "memory"); \
} while (0)

// Flag barrier: full drain so r0's agent-scope release publishes all waves'
// stores. In the deferred-flag scheme the stores being drained were issued a
// full step earlier -> the vmcnt(0) wait is ~free.
#define BARRIER_ALL() do { \
    asm volatile("s_waitcnt vmcnt(0) lgkmcnt(0)" ::: "memory"); \
    __builtin_amdgcn_s_barrier(); \
    asm volatile("" ::: "memory"); \
} while (0)

// Load one float4 of weights as two packed f2 pairs, pinned in the reg file.
#define DECLW4(nm, src) \
    float4 _t_##nm = (src); \
    f2 nm##_a = {_t_##nm.x, _t_##nm.y}; \
    f2 nm##_b = {_t_##nm.z, _t_##nm.w}; \
    asm volatile("" : "+v"(nm##_a), "+v"(nm##_b));

// Gate-aligned weight residency: thread (rg,p) holds rows {rg,rg+128,rg+256,rg+384},
// k-slice [32p, 32p+32) -> 128 floats/thread as 64 f2 pairs.
#define LOADW_ALL(W) \
    const float4* wpa_ = (const float4*)((W) + (size_t)(rg)       * H + p * 32); \
    const float4* wpb_ = (const float4*)((W) + (size_t)(rg + 128) * H + p * 32); \
    const float4* wpc_ = (const float4*)((W) + (size_t)(rg + 256) * H + p * 32); \
    const float4* wpd_ = (const float4*)((W) + (size_t)(rg + 384) * H + p * 32); \
    DECLW4(wa0, wpa_[0]) DECLW4(wa1, wpa_[1]) DECLW4(wa2, wpa_[2]) DECLW4(wa3, wpa_[3]) \
    DECLW4(wa4, wpa_[4]) DECLW4(wa5, wpa_[5]) DECLW4(wa6, wpa_[6]) DECLW4(wa7, wpa_[7]) \
    DECLW4(wb0, wpb_[0]) DECLW4(wb1, wpb_[1]) DECLW4(wb2, wpb_[2]) DECLW4(wb3, wpb_[3]) \
    DECLW4(wb4, wpb_[4]) DECLW4(wb5, wpb_[5]) DECLW4(wb6, wpb_[6]) DECLW4(wb7, wpb_[7]) \
    DECLW4(wc0, wpc_[0]) DECLW4(wc1, wpc_[1]) DECLW4(wc2, wpc_[2]) DECLW4(wc3, wpc_[3]) \
    DECLW4(wc4, wpc_[4]) DECLW4(wc5, wpc_[5]) DECLW4(wc6, wpc_[6]) DECLW4(wc7, wpc_[7]) \
    DECLW4(wd0, wpd_[0]) DECLW4(wd1, wpd_[1]) DECLW4(wd2, wpd_[2]) DECLW4(wd3, wpd_[3]) \
    DECLW4(wd4, wpd_[4]) DECLW4(wd5, wpd_[5]) DECLW4(wd6, wpd_[6]) DECLW4(wd7, wpd_[7])

// Packed dual-FMA: acc(lo,hi) += w(lo,hi) * h(lo,hi).
#define PKFMA(acc, w, h) \
    asm("v_pk_fma_f32 %0, %1, %2, %0" : "+v"(acc) : "v"(w), "v"(h));

#define FMA1(nm, hA, hB, acc) PKFMA(acc, nm##_a, hA) PKFMA(acc, nm##_b, hB)

#define DOTJ(j) { \
    f2 hA_ = {hv##j.x, hv##j.y}; f2 hB_ = {hv##j.z, hv##j.w}; \
    FMA1(wa##j, hA_, hB_, q0) FMA1(wb##j, hA_, hB_, q1) \
    FMA1(wc##j, hA_, hB_, q2) FMA1(wd##j, hA_, hB_, q3) }

// 8 b128 broadcast reads + 64 pk_fma + quad reduction -> a0..a3 = full gate dots
#define DOT_BODY(HBASE) \
    const float4* _hp4 = (const float4*)(HBASE); \
    float4 hv0=_hp4[0],hv1=_hp4[1],hv2=_hp4[2],hv3=_hp4[3], \
           hv4=_hp4[4],hv5=_hp4[5],hv6=_hp4[6],hv7=_hp4[7]; \
    f2 q0={0.f,0.f},q1={0.f,0.f},q2={0.f,0.f},q3={0.f,0.f}; \
    DOTJ(0) DOTJ(1) DOTJ(2) DOTJ(3) DOTJ(4) DOTJ(5) DOTJ(6) DOTJ(7) \
    float a0=q0.x+q0.y, a1=q1.x+q1.y, a2=q2.x+q2.y, a3=q3.x+q3.y; \
    a0 = quad_sum(a0); a1 = quad_sum(a1); a2 = quad_sum(a2); a3 = quad_sum(a3);

// ---------------------------------------------------------------------------
// Overlapped 4-role pipeline, one CU per (role,batch): 32 blocks x 512 thr.
//   role 0 = A : layer-1 recurrence (w_hh0)        -> h1[t], v[t]
//   role 1 = B1: w_ih1 @ h1 (chunked)              -> parts[.., 0:512)
//   role 2 = B2: w_ih1 @ v  (chunked)              -> parts[.., 512:1024)
//   role 3 = C : w_hh1 @ h2 + elementwise -> DIAGONAL-only output scatter
// Output zeros are pre-written by hipMemsetAsync before this kernel.
// DEFERRED-FLAG: every step publishes step t-1's h1v at its top; the chunk
// flag is released one step late (end of step t, t%CH==0) so the vmcnt(0)
// drain always covers stores issued a full step earlier (~free).
// ---------------------------------------------------------------------------
__global__ __launch_bounds__(512)
__attribute__((amdgpu_waves_per_eu(1, 2)))
void pipe_kernel(const float* __restrict__ x,
                 const float* __restrict__ w_ih0,
                 const float* __restrict__ w_hh0,
                 const float* __restrict__ b_ih0,
                 const float* __restrict__ b_hh0,
                 const float* __restrict__ w_ih1,
                 const float* __restrict__ w_hh1,
                 const float* __restrict__ b_ih1,
                 const float* __restrict__ b_hh1,
                 const float* __restrict__ w_out,
                 float* __restrict__ ws,
                 float* __restrict__ outp) {
    const int role = blockIdx.x >> 3;
    const int b    = blockIdx.x & 7;
    const int r    = threadIdx.x;
    const int rg   = r >> 2, p = r & 3;
    const int wsl  = rg >> 5, wpos = rg & 31;

    int* cntA  = (int*)ws + OFF_CNT       + b * 32;
    int* cntB1 = (int*)ws + OFF_CNT + 256 + b * 32;
    int* cntB2 = (int*)ws + OFF_CNT + 512 + b * 32;
    float* h1v = ws + OFF_H1V + (size_t)b * TT * 256;

    __shared__ float hbuf[2][144];    // recurrent state, 4 padded slices x 36
    __shared__ float u_s[TT];
    __shared__ float scr[512];
    __shared__ float hb[CH * 144];    // B chunk staging
    __shared__ float gbuf[CH][128];   // C: per-chunk unreduced g

    if (role == 0) {
        // ===================== Stage A: layer-1 recurrence =====================
        LOADW_ALL(w_hh0)
        const float b0 = b_ih0[rg]       + b_hh0[rg];
        const float b1 = b_ih0[rg + 128] + b_hh0[rg + 128];
        const float b2 = b_ih0[rg + 256] + b_hh0[rg + 256];
        const float b3 = b_ih0[rg + 384] + b_hh0[rg + 384];
        const float wi0 = w_ih0[rg], wi1 = w_ih0[rg + 128];
        const float wi2 = w_ih0[rg + 256], wi3 = w_ih0[rg + 384];
        {   // u[t] = trace(x[b,t]) cooperatively (4 partials per t)
            const float* xb = x + (size_t)(b * TT + (r & 127)) * 1024;
            const int pq = r >> 7;
            float u = 0.f;
#pragma unroll
            for (int i = 0; i < 8; i++) u += xb[(pq * 8 + i) * 33];
            scr[r] = u;
        }
        if (r < 144) hbuf[0][r] = 0.f;
        __syncthreads();
        if (r < TT) u_s[r] = scr[r] + scr[r + 128] + scr[r + 256] + scr[r + 384];
        __syncthreads();

        float c1 = 0.f;
        float hn_prev = 0.f, vn_prev = 0.f;
        for (int t = 0; t < TT; t++) {
            // publish PREVIOUS step's h1v (issues during this step's work;
            // retires in the shadow of the dot below — never drained fresh)
            if (t > 0) {
                if (p == 0) h1v[(t - 1) * 256 + rg] = hn_prev;
                if (p == 1) h1v[(t - 1) * 256 + 128 + rg] = vn_prev;
            }
            const float u = u_s[t];
            const float* hc = hbuf[t & 1];
            float* hx = hbuf[(t & 1) ^ 1];
            DOT_BODY(hc + p * 36)
            float z0 = a0 + fmaf(wi0, u, b0);
            float z1 = a1 + fmaf(wi1, u, b1);
            float z2 = a2 + fmaf(wi2, u, b2);
            float z3 = a3 + fmaf(wi3, u, b3);
            float gi = sigf(z0), gf = sigf(z1), gg = tanhf_fast(z2), go = sigf(z3);
            float di = gi * (1.f - gi) * wi0, df = gf * (1.f - gf) * wi1;
            float dg = (1.f - gg * gg) * wi2, dd = go * (1.f - go) * wi3;
            float dc = df * c1 + di * gg + gi * dg;
            c1 = gf * c1 + gi * gg;
            float th = tanhf_fast(c1);
            float hn = go * th;
            float vn = dd * th + go * (1.f - th * th) * dc;
            if (p == wsl) hx[p * 36 + wpos] = hn;       // one writer per h-index
            hn_prev = hn; vn_prev = vn;
            if ((t & (CH - 1)) == 0 && t > 0) {
                // deferred flag: chunk (t/CH - 1)'s last store was issued at
                // the TOP of this step -> vmcnt(0) here is ~free.
                BARRIER_ALL();
                if (r == 0)
                    __hip_atomic_store(cntA, t, __ATOMIC_RELEASE, __HIP_MEMORY_SCOPE_AGENT);
            } else {
                BARRIER_LGKM();  // LDS recurrence state only — no vmcnt drain
            }
        }
        // epilogue: publish final step, drain, release final flag
        if (p == 0) h1v[(TT - 1) * 256 + rg] = hn_prev;
        if (p == 1) h1v[(TT - 1) * 256 + 128 + rg] = vn_prev;
        BARRIER_ALL();
        if (r == 0)
            __hip_atomic_store(cntA, TT, __ATOMIC_RELEASE, __HIP_MEMORY_SCOPE_AGENT);
    } else if (role == 1 || role == 2) {
        // ============ Stages B1/B2: w_ih1 @ (h1 | v), chunk-parallel ============
        LOADW_ALL(w_ih1)
        int* myCnt = (role == 2) ? cntB2 : cntB1;
        const float* hsrc = h1v + ((role == 2) ? 128 : 0);
        float* pbase = ws + OFF_PARTS + (size_t)b * TT * 1024 + ((role == 2) ? 512 : 0);
        for (int c = 0; c < NCH; c++) {
            if (r == 0) wait_ge(cntA, (c + 1) * CH);
            __syncthreads();
            if (r < 256) {   // stage chunk into padded slices
                int tl = r >> 5, k4 = r & 31, s = k4 >> 3, j = k4 & 7;
                float4 v = *(const float4*)(hsrc + (size_t)(c * CH + tl) * 256 + k4 * 4);
                *(float4*)&hb[(tl * 4 + s) * 36 + j * 4] = v;
            }
            __syncthreads();
#pragma unroll
            for (int tl = 0; tl < CH; tl++) {
                DOT_BODY(hb + (tl * 4 + p) * 36)
                // lane p stores gate-p's dot -> C reads 4 gates back as ONE float4
                float sel = (p == 0) ? a0 : (p == 1) ? a1 : (p == 2) ? a2 : a3;
                pbase[(size_t)(c * CH + tl) * 1024 + r] = sel;
            }
            BARRIER_ALL();   // drain all chunk stores before flag
            if (r == 0)
                __hip_atomic_store(myCnt, (c + 1) * CH, __ATOMIC_RELEASE, __HIP_MEMORY_SCOPE_AGENT);
        }
    } else {
        // ==== Stage C: w_hh1 @ h2 + layer-2 elementwise + diag-only scatter ====
        LOADW_ALL(w_hh1)
        const float b0 = b_ih1[rg]       + b_hh1[rg];
        const float b1 = b_ih1[rg + 128] + b_hh1[rg + 128];
        const float b2 = b_ih1[rg + 256] + b_hh1[rg + 256];
        const float b3 = b_ih1[rg + 384] + b_hh1[rg + 384];
        const float wo = w_out[rg];
        if (r < 144) hbuf[0][r] = 0.f;
        __syncthreads();
        const float* parts = ws + OFF_PARTS + (size_t)b * TT * 1024;
        float c2 = 0.f;
        for (int c = 0; c < NCH; c++) {
            if (r == 0) { wait_ge(cntB1, (c + 1) * CH); wait_ge(cntB2, (c + 1) * CH); }
            __syncthreads();
            float4 zf[CH], af[CH];   // prefetch whole chunk's partials (hide L2 lat)
#pragma unroll
            for (int tl = 0; tl < CH; tl++) {
                zf[tl] = *(const float4*)(parts + (size_t)(c * CH + tl) * 1024 + rg * 4);
                af[tl] = *(const float4*)(parts + (size_t)(c * CH + tl) * 1024 + 512 + rg * 4);
            }
#pragma unroll
            for (int tl = 0; tl < CH; tl++) {
                const int t = c * CH + tl;
                const float* hc = hbuf[t & 1];
                float* hx = hbuf[(t & 1) ^ 1];
                DOT_BODY(hc + p * 36)
                float z0 = a0 + b0 + zf[tl].x;
                float z1 = a1 + b1 + zf[tl].y;
                float z2 = a2 + b2 + zf[tl].z;
                float z3 = a3 + b3 + zf[tl].w;
                float gi = sigf(z0), gf = sigf(z1), gg = tanhf_fast(z2), go = sigf(z3);
                float di = gi * (1.f - gi) * af[tl].x, df = gf * (1.f - gf) * af[tl].y;
                float dg = (1.f - gg * gg) * af[tl].z, dd = go * (1.f - go) * af[tl].w;
                float dc = df * c2 + di * gg + gi * dg;
                c2 = gf * c2 + gi * gg;
                float th = tanhf_fast(c2);
                if (p == wsl) hx[p * 36 + wpos] = go * th;
                float dh2 = dd * th + go * (1.f - th * th) * dc;
                if (p == 0) gbuf[tl][rg] = wo * dh2;   // unreduced, LDS
                BARRIER_LGKM();   // hbuf + gbuf are LDS-only -> no vmcnt drain
            }
            // ---- reduce chunk's g and scatter ONLY the 32 diagonal scalars ----
            {
                const int w = r >> 6, l = r & 63;      // wave w handles t-local w
                float v = gbuf[w][l] + gbuf[w][l + 64];
                v = quad_sum(v);
                v += __shfl_xor(v, 4, 64);
                v += __shfl_xor(v, 8, 64);
                v += __shfl_xor(v, 16, 64);
                v += __shfl_xor(v, 32, 64);
                if (l == 0) scr[w] = v;
                BARRIER_LGKM();
                if (r < 256) {                          // 8 t x 32 diag elements
                    const int tl = r >> 5, d = r & 31;
                    outp[(size_t)(b * TT + c * CH + tl) * 1024 + d * 33] = scr[tl];
                }
            }
        }
    }
}

extern "C" void kernel_launch(void* const* d_in, const int* in_sizes, int n_in,
                              void* d_out, int out_size, void* d_ws, size_t ws_size,
                              hipStream_t stream) {
    const float* x     = (const float*)d_in[0];
    const float* w_ih0 = (const float*)d_in[1];
    const float* w_hh0 = (const float*)d_in[2];
    const float* b_ih0 = (const float*)d_in[3];
    const float* b_hh0 = (const float*)d_in[4];
    const float* w_ih1 = (const float*)d_in[5];
    const float* w_hh1 = (const float*)d_in[6];
    const float* b_ih1 = (const float*)d_in[7];
    const float* b_hh1 = (const float*)d_in[8];
    const float* w_out = (const float*)d_in[9];
    // d_in[10] = b_out: constant offset, zero derivative -> unused

    float* ws = (float*)d_ws;   // counters rely on 0xAA poison (<0 as int)

    // Zero the output (31/32 of it stays zero; pipe_kernel scatters diagonals).
    hipMemsetAsync(d_out, 0, (size_t)out_size, stream);

    pipe_kernel<<<dim3(32), dim3(512), 0, stream>>>(x, w_ih0, w_hh0, b_ih0, b_hh0,
                                                    w_ih1, w_hh1, b_ih1, b_hh1, w_out,
                                                    ws, (float*)d_out);
}

// Round 10
// 224.761 us; speedup vs baseline: 1.6363x; 1.0469x over previous
//
#include <hip/hip_runtime.h>
#include <math.h>

#define H    128
#define TT   128
#define CH   8            // steps per chunk/flag
#define NCH  (TT / CH)    // 16

// ws float offsets
#define OFF_H1V   0                 // [b][t][256]  h1 | v      : 262144 floats
#define OFF_PARTS 262144            // [b][t][1024] z2 | ad     : 1048576 floats
#define OFF_CNT   1441792           // int counters (poisoned 0xAA -> negative)

typedef __attribute__((ext_vector_type(2))) float f2;

// raw v_rcp_f32 (~1 ulp) instead of Newton-refined divide: shorter serial chain
__device__ __forceinline__ float rcpf(float x) { return __builtin_amdgcn_rcpf(x); }
__device__ __forceinline__ float sigf(float x)       { return rcpf(1.0f + __expf(-x)); }
__device__ __forceinline__ float tanhf_fast(float x) { return 1.0f - 2.0f * rcpf(1.0f + __expf(2.0f * x)); }

// sum over the 4-lane p-group via DPP quad_perm (VALU, no LDS traffic)
__device__ __forceinline__ float quad_sum(float v) {
    int t = __builtin_amdgcn_update_dpp(0, __float_as_int(v), 0xB1, 0xF, 0xF, true); // xor 1
    v += __int_as_float(t);
    t = __builtin_amdgcn_update_dpp(0, __float_as_int(v), 0x4E, 0xF, 0xF, true);     // xor 2
    v += __int_as_float(t);
    return v;
}

// Cheap spin: RELAXED polls, then ONE acquire load for the synchronizes-with edge.
__device__ __forceinline__ void wait_ge(int* ptr, int val) {
    while (__hip_atomic_load(ptr, __ATOMIC_RELAXED, __HIP_MEMORY_SCOPE_AGENT) < val)
        __builtin_amdgcn_s_sleep(1);
    (void)__hip_atomic_load(ptr, __ATOMIC_ACQUIRE, __HIP_MEMORY_SCOPE_AGENT);
}

// Per-step barrier: LDS-only drain (global stores stay in flight until chunk end).
#define BARRIER_LGKM() do { \
    asm volatile("s_waitcnt lgkmcnt(0)" ::: "memory"); \
    __builtin_amdgcn_s_barrier(); \
    asm volatile("" ::: "memory"); \
} while (0)

// Flag barrier: full drain so r0's agent-scope release publishes all waves'
// stores. With deferred flags the drained stores were issued a step earlier.
#define BARRIER_ALL() do { \
    asm volatile("s_waitcnt vmcnt(0) lgkmcnt(0)" ::: "memory"); \
    __builtin_amdgcn_s_barrier(); \
    asm volatile("" ::: "memory"); \
} while (0)

// Load one float4 of weights as two packed f2 pairs, pinned in the reg file.
#define DECLW4(nm, src) \
    float4 _t_##nm = (src); \
    f2 nm##_a = {_t_##nm.x, _t_##nm.y}; \
    f2 nm##_b = {_t_##nm.z, _t_##nm.w}; \
    asm volatile("" : "+v"(nm##_a), "+v"(nm##_b));

// Gate-aligned weight residency: thread (rg,p) holds rows {rg,rg+128,rg+256,rg+384},
// k-slice [32p, 32p+32) -> 128 floats/thread as 64 f2 pairs.
#define LOADW_ALL(W) \
    const float4* wpa_ = (const float4*)((W) + (size_t)(rg)       * H + p * 32); \
    const float4* wpb_ = (const float4*)((W) + (size_t)(rg + 128) * H + p * 32); \
    const float4* wpc_ = (const float4*)((W) + (size_t)(rg + 256) * H + p * 32); \
    const float4* wpd_ = (const float4*)((W) + (size_t)(rg + 384) * H + p * 32); \
    DECLW4(wa0, wpa_[0]) DECLW4(wa1, wpa_[1]) DECLW4(wa2, wpa_[2]) DECLW4(wa3, wpa_[3]) \
    DECLW4(wa4, wpa_[4]) DECLW4(wa5, wpa_[5]) DECLW4(wa6, wpa_[6]) DECLW4(wa7, wpa_[7]) \
    DECLW4(wb0, wpb_[0]) DECLW4(wb1, wpb_[1]) DECLW4(wb2, wpb_[2]) DECLW4(wb3, wpb_[3]) \
    DECLW4(wb4, wpb_[4]) DECLW4(wb5, wpb_[5]) DECLW4(wb6, wpb_[6]) DECLW4(wb7, wpb_[7]) \
    DECLW4(wc0, wpc_[0]) DECLW4(wc1, wpc_[1]) DECLW4(wc2, wpc_[2]) DECLW4(wc3, wpc_[3]) \
    DECLW4(wc4, wpc_[4]) DECLW4(wc5, wpc_[5]) DECLW4(wc6, wpc_[6]) DECLW4(wc7, wpc_[7]) \
    DECLW4(wd0, wpd_[0]) DECLW4(wd1, wpd_[1]) DECLW4(wd2, wpd_[2]) DECLW4(wd3, wpd_[3]) \
    DECLW4(wd4, wpd_[4]) DECLW4(wd5, wpd_[5]) DECLW4(wd6, wpd_[6]) DECLW4(wd7, wpd_[7])

// Packed dual-FMA: acc(lo,hi) += w(lo,hi) * h(lo,hi).
#define PKFMA(acc, w, h) \
    asm("v_pk_fma_f32 %0, %1, %2, %0" : "+v"(acc) : "v"(w), "v"(h));

#define FMA1(nm, hA, hB, acc) PKFMA(acc, nm##_a, hA) PKFMA(acc, nm##_b, hB)

#define DOTJ(j) { \
    f2 hA_ = {hv##j.x, hv##j.y}; f2 hB_ = {hv##j.z, hv##j.w}; \
    FMA1(wa##j, hA_, hB_, q0) FMA1(wb##j, hA_, hB_, q1) \
    FMA1(wc##j, hA_, hB_, q2) FMA1(wd##j, hA_, hB_, q3) }

// 8 b128 broadcast reads + 64 pk_fma + quad reduction -> a0..a3 = full gate dots
#define DOT_BODY(HBASE) \
    const float4* _hp4 = (const float4*)(HBASE); \
    float4 hv0=_hp4[0],hv1=_hp4[1],hv2=_hp4[2],hv3=_hp4[3], \
           hv4=_hp4[4],hv5=_hp4[5],hv6=_hp4[6],hv7=_hp4[7]; \
    f2 q0={0.f,0.f},q1={0.f,0.f},q2={0.f,0.f},q3={0.f,0.f}; \
    DOTJ(0) DOTJ(1) DOTJ(2) DOTJ(3) DOTJ(4) DOTJ(5) DOTJ(6) DOTJ(7) \
    float a0=q0.x+q0.y, a1=q1.x+q1.y, a2=q2.x+q2.y, a3=q3.x+q3.y; \
    a0 = quad_sum(a0); a1 = quad_sum(a1); a2 = quad_sum(a2); a3 = quad_sum(a3);

// ---------------------------------------------------------------------------
// Overlapped 4-role pipeline, one CU per (role,batch): 32 blocks x 512 thr.
//   role 0 = A : layer-1 recurrence (w_hh0)        -> h1[t], v[t]
//   role 1 = B1: w_ih1 @ h1 (chunked)              -> parts[.., 0:512)
//   role 2 = B2: w_ih1 @ v  (chunked)              -> parts[.., 512:1024)
//   role 3 = C : w_hh1 @ h2 + elementwise -> DIAGONAL-only output scatter
// Output zeros are pre-written by hipMemsetAsync before this kernel.
// C is the binding stage: its chunk-end reduce+scatter is moved OFF the
// serial path (double-buffered gbuf; reduce of chunk c-1 overlaps the flag
// wait for chunk c, spinners = lanes 448/449 so waves 0-6 reduce in parallel).
// ---------------------------------------------------------------------------
__global__ __launch_bounds__(512)
__attribute__((amdgpu_waves_per_eu(1, 2)))
void pipe_kernel(const float* __restrict__ x,
                 const float* __restrict__ w_ih0,
                 const float* __restrict__ w_hh0,
                 const float* __restrict__ b_ih0,
                 const float* __restrict__ b_hh0,
                 const float* __restrict__ w_ih1,
                 const float* __restrict__ w_hh1,
                 const float* __restrict__ b_ih1,
                 const float* __restrict__ b_hh1,
                 const float* __restrict__ w_out,
                 float* __restrict__ ws,
                 float* __restrict__ outp) {
    const int role = blockIdx.x >> 3;
    const int b    = blockIdx.x & 7;
    const int r    = threadIdx.x;
    const int rg   = r >> 2, p = r & 3;
    const int wsl  = rg >> 5, wpos = rg & 31;

    int* cntA  = (int*)ws + OFF_CNT       + b * 32;
    int* cntB1 = (int*)ws + OFF_CNT + 256 + b * 32;
    int* cntB2 = (int*)ws + OFF_CNT + 512 + b * 32;
    float* h1v = ws + OFF_H1V + (size_t)b * TT * 256;

    __shared__ float hbuf[2][144];    // recurrent state, 4 padded slices x 36
    __shared__ float u_s[TT];
    __shared__ float scr[512];
    __shared__ float hb[CH * 144];    // B chunk staging
    __shared__ float gbuf[2][CH][128]; // C: double-buffered unreduced g

    if (role == 0) {
        // ===================== Stage A: layer-1 recurrence =====================
        LOADW_ALL(w_hh0)
        const float b0 = b_ih0[rg]       + b_hh0[rg];
        const float b1 = b_ih0[rg + 128] + b_hh0[rg + 128];
        const float b2 = b_ih0[rg + 256] + b_hh0[rg + 256];
        const float b3 = b_ih0[rg + 384] + b_hh0[rg + 384];
        const float wi0 = w_ih0[rg], wi1 = w_ih0[rg + 128];
        const float wi2 = w_ih0[rg + 256], wi3 = w_ih0[rg + 384];
        {   // u[t] = trace(x[b,t]) cooperatively (4 partials per t)
            const float* xb = x + (size_t)(b * TT + (r & 127)) * 1024;
            const int pq = r >> 7;
            float u = 0.f;
#pragma unroll
            for (int i = 0; i < 8; i++) u += xb[(pq * 8 + i) * 33];
            scr[r] = u;
        }
        if (r < 144) hbuf[0][r] = 0.f;
        __syncthreads();
        if (r < TT) u_s[r] = scr[r] + scr[r + 128] + scr[r + 256] + scr[r + 384];
        __syncthreads();

        float c1 = 0.f;
        float hn_prev = 0.f, vn_prev = 0.f;
        for (int t = 0; t < TT; t++) {
            // publish PREVIOUS step's h1v (retires in this step's shadow)
            if (t > 0) {
                if (p == 0) h1v[(t - 1) * 256 + rg] = hn_prev;
                if (p == 1) h1v[(t - 1) * 256 + 128 + rg] = vn_prev;
            }
            const float u = u_s[t];
            const float* hc = hbuf[t & 1];
            float* hx = hbuf[(t & 1) ^ 1];
            DOT_BODY(hc + p * 36)
            float z0 = a0 + fmaf(wi0, u, b0);
            float z1 = a1 + fmaf(wi1, u, b1);
            float z2 = a2 + fmaf(wi2, u, b2);
            float z3 = a3 + fmaf(wi3, u, b3);
            float gi = sigf(z0), gf = sigf(z1), gg = tanhf_fast(z2), go = sigf(z3);
            float di = gi * (1.f - gi) * wi0, df = gf * (1.f - gf) * wi1;
            float dg = (1.f - gg * gg) * wi2, dd = go * (1.f - go) * wi3;
            float dc = df * c1 + di * gg + gi * dg;
            c1 = gf * c1 + gi * gg;
            float th = tanhf_fast(c1);
            float hn = go * th;
            float vn = dd * th + go * (1.f - th * th) * dc;
            if (p == wsl) hx[p * 36 + wpos] = hn;       // one writer per h-index
            hn_prev = hn; vn_prev = vn;
            if ((t & (CH - 1)) == 0 && t > 0) {
                // deferred flag: chunk (t/CH - 1)'s last store was issued at
                // the TOP of this step -> vmcnt(0) here is ~free.
                BARRIER_ALL();
                if (r == 0)
                    __hip_atomic_store(cntA, t, __ATOMIC_RELEASE, __HIP_MEMORY_SCOPE_AGENT);
            } else {
                BARRIER_LGKM();  // LDS recurrence state only — no vmcnt drain
            }
        }
        // epilogue: publish final step, drain, release final flag
        if (p == 0) h1v[(TT - 1) * 256 + rg] = hn_prev;
        if (p == 1) h1v[(TT - 1) * 256 + 128 + rg] = vn_prev;
        BARRIER_ALL();
        if (r == 0)
            __hip_atomic_store(cntA, TT, __ATOMIC_RELEASE, __HIP_MEMORY_SCOPE_AGENT);
    } else if (role == 1 || role == 2) {
        // ============ Stages B1/B2: w_ih1 @ (h1 | v), chunk-parallel ============
        LOADW_ALL(w_ih1)
        int* myCnt = (role == 2) ? cntB2 : cntB1;
        const float* hsrc = h1v + ((role == 2) ? 128 : 0);
        float* pbase = ws + OFF_PARTS + (size_t)b * TT * 1024 + ((role == 2) ? 512 : 0);
        for (int c = 0; c < NCH; c++) {
            if (r == 0) wait_ge(cntA, (c + 1) * CH);
            __syncthreads();
            if (r < 256) {   // stage chunk into padded slices
                int tl = r >> 5, k4 = r & 31, s = k4 >> 3, j = k4 & 7;
                float4 v = *(const float4*)(hsrc + (size_t)(c * CH + tl) * 256 + k4 * 4);
                *(float4*)&hb[(tl * 4 + s) * 36 + j * 4] = v;
            }
            __syncthreads();
#pragma unroll
            for (int tl = 0; tl < CH; tl++) {
                DOT_BODY(hb + (tl * 4 + p) * 36)
                // lane p stores gate-p's dot -> C reads 4 gates back as ONE float4
                float sel = (p == 0) ? a0 : (p == 1) ? a1 : (p == 2) ? a2 : a3;
                pbase[(size_t)(c * CH + tl) * 1024 + r] = sel;
            }
            BARRIER_ALL();   // drain all chunk stores before flag
            if (r == 0)
                __hip_atomic_store(myCnt, (c + 1) * CH, __ATOMIC_RELEASE, __HIP_MEMORY_SCOPE_AGENT);
        }
    } else {
        // ==== Stage C: w_hh1 @ h2 + layer-2 elementwise + diag-only scatter ====
        LOADW_ALL(w_hh1)
        const float b0 = b_ih1[rg]       + b_hh1[rg];
        const float b1 = b_ih1[rg + 128] + b_hh1[rg + 128];
        const float b2 = b_ih1[rg + 256] + b_hh1[rg + 256];
        const float b3 = b_ih1[rg + 384] + b_hh1[rg + 384];
        const float wo = w_out[rg];
        if (r < 144) hbuf[0][r] = 0.f;
        __syncthreads();
        const float* parts = ws + OFF_PARTS + (size_t)b * TT * 1024;
        float c2 = 0.f;
        for (int c = 0; c < NCH; c++) {
            // ---- flag spin (lanes 448/449, wave 7) IN PARALLEL with the ----
            // ---- reduce of the PREVIOUS chunk's gbuf by waves 0..6 ---------
            if (r == 448) wait_ge(cntB1, (c + 1) * CH);
            if (r == 449) wait_ge(cntB2, (c + 1) * CH);
            if (c > 0) {
                const int w = r >> 6, l = r & 63;      // wave w reduces t-local w
                float v = gbuf[(c - 1) & 1][w][l] + gbuf[(c - 1) & 1][w][l + 64];
                v = quad_sum(v);
                v += __shfl_xor(v, 4, 64);
                v += __shfl_xor(v, 8, 64);
                v += __shfl_xor(v, 16, 64);
                v += __shfl_xor(v, 32, 64);
                if (l == 0) scr[w] = v;
            }
            __syncthreads();   // flags acquired + scr complete
            if (c > 0 && r < 256) {   // scatter prev chunk's 8t x 32 diagonals
                const int tl = r >> 5, d = r & 31;
                outp[(size_t)(b * TT + (c - 1) * CH + tl) * 1024 + d * 33] = scr[tl];
            }
            float4 zf[CH], af[CH];   // prefetch whole chunk's partials (hide L2 lat)
#pragma unroll
            for (int tl = 0; tl < CH; tl++) {
                zf[tl] = *(const float4*)(parts + (size_t)(c * CH + tl) * 1024 + rg * 4);
                af[tl] = *(const float4*)(parts + (size_t)(c * CH + tl) * 1024 + 512 + rg * 4);
            }
#pragma unroll
            for (int tl = 0; tl < CH; tl++) {
                const int t = c * CH + tl;
                const float* hc = hbuf[t & 1];
                float* hx = hbuf[(t & 1) ^ 1];
                DOT_BODY(hc + p * 36)
                float z0 = a0 + b0 + zf[tl].x;
                float z1 = a1 + b1 + zf[tl].y;
                float z2 = a2 + b2 + zf[tl].z;
                float z3 = a3 + b3 + zf[tl].w;
                float gi = sigf(z0), gf = sigf(z1), gg = tanhf_fast(z2), go = sigf(z3);
                float di = gi * (1.f - gi) * af[tl].x, df = gf * (1.f - gf) * af[tl].y;
                float dg = (1.f - gg * gg) * af[tl].z, dd = go * (1.f - go) * af[tl].w;
                float dc = df * c2 + di * gg + gi * dg;
                c2 = gf * c2 + gi * gg;
                float th = tanhf_fast(c2);
                if (p == wsl) hx[p * 36 + wpos] = go * th;
                float dh2 = dd * th + go * (1.f - th * th) * dc;
                if (p == 0) gbuf[c & 1][tl][rg] = wo * dh2;   // unreduced, LDS
                BARRIER_LGKM();   // hbuf + gbuf are LDS-only -> no vmcnt drain
            }
        }
        // ---- final chunk's reduce + scatter (no next chunk to overlap) ----
        {
            const int w = r >> 6, l = r & 63;
            float v = gbuf[(NCH - 1) & 1][w][l] + gbuf[(NCH - 1) & 1][w][l + 64];
            v = quad_sum(v);
            v += __shfl_xor(v, 4, 64);
            v += __shfl_xor(v, 8, 64);
            v += __shfl_xor(v, 16, 64);
            v += __shfl_xor(v, 32, 64);
            if (l == 0) scr[w] = v;
            BARRIER_LGKM();
            if (r < 256) {
                const int tl = r >> 5, d = r & 31;
                outp[(size_t)(b * TT + (NCH - 1) * CH + tl) * 1024 + d * 33] = scr[tl];
            }
        }
    }
}

extern "C" void kernel_launch(void* const* d_in, const int* in_sizes, int n_in,
                              void* d_out, int out_size, void* d_ws, size_t ws_size,
                              hipStream_t stream) {
    const float* x     = (const float*)d_in[0];
    const float* w_ih0 = (const float*)d_in[1];
    const float* w_hh0 = (const float*)d_in[2];
    const float* b_ih0 = (const float*)d_in[3];
    const float* b_hh0 = (const float*)d_in[4];
    const float* w_ih1 = (const float*)d_in[5];
    const float* w_hh1 = (const float*)d_in[6];
    const float* b_ih1 = (const float*)d_in[7];
    const float* b_hh1 = (const float*)d_in[8];
    const float* w_out = (const float*)d_in[9];
    // d_in[10] = b_out: constant offset, zero derivative -> unused

    float* ws = (float*)d_ws;   // counters rely on 0xAA poison (<0 as int)

    // Zero the output (31/32 of it stays zero; pipe_kernel scatters diagonals).
    hipMemsetAsync(d_out, 0, (size_t)out_size, stream);

    pipe_kernel<<<dim3(32), dim3(512), 0, stream>>>(x, w_ih0, w_hh0, b_ih0, b_hh0,
                                                    w_ih1, w_hh1, b_ih1, b_hh1, w_out,
                                                    ws, (float*)d_out);
}

// Round 11
// 217.218 us; speedup vs baseline: 1.6932x; 1.0347x over previous
//
#include <hip/hip_runtime.h>
#include <math.h>

#define H    128
#define TT   128
#define CH   8            // main chunk size; tail tapers to 2x4

// ws float offsets
#define OFF_H1V   0                 // [b][t][256]  h1 | v      : 262144 floats
#define OFF_PARTS 262144            // [b][t][1024] z2 | ad     : 1048576 floats
#define OFF_CNT   1441792           // int counters (poisoned 0xAA -> negative)

typedef __attribute__((ext_vector_type(2))) float f2;

// raw v_rcp_f32 (~1 ulp) instead of Newton-refined divide: shorter serial chain
__device__ __forceinline__ float rcpf(float x) { return __builtin_amdgcn_rcpf(x); }
__device__ __forceinline__ float sigf(float x)       { return rcpf(1.0f + __expf(-x)); }
__device__ __forceinline__ float tanhf_fast(float x) { return 1.0f - 2.0f * rcpf(1.0f + __expf(2.0f * x)); }

// sum over the 4-lane p-group via DPP quad_perm (VALU, no LDS traffic)
__device__ __forceinline__ float quad_sum(float v) {
    int t = __builtin_amdgcn_update_dpp(0, __float_as_int(v), 0xB1, 0xF, 0xF, true); // xor 1
    v += __int_as_float(t);
    t = __builtin_amdgcn_update_dpp(0, __float_as_int(v), 0x4E, 0xF, 0xF, true);     // xor 2
    v += __int_as_float(t);
    return v;
}

// Cheap spin: RELAXED polls, then ONE acquire load for the synchronizes-with edge.
__device__ __forceinline__ void wait_ge(int* ptr, int val) {
    while (__hip_atomic_load(ptr, __ATOMIC_RELAXED, __HIP_MEMORY_SCOPE_AGENT) < val)
        __builtin_amdgcn_s_sleep(1);
    (void)__hip_atomic_load(ptr, __ATOMIC_ACQUIRE, __HIP_MEMORY_SCOPE_AGENT);
}

// Per-step barrier: LDS-only drain (global stores stay in flight until chunk end).
#define BARRIER_LGKM() do { \
    asm volatile("s_waitcnt lgkmcnt(0)" ::: "memory"); \
    __builtin_amdgcn_s_barrier(); \
    asm volatile("" ::: "memory"); \
} while (0)

// Flag barrier: full drain so r0's agent-scope release publishes all waves'
// stores. With deferred flags the drained stores were issued a step earlier.
#define BARRIER_ALL() do { \
    asm volatile("s_waitcnt vmcnt(0) lgkmcnt(0)" ::: "memory"); \
    __builtin_amdgcn_s_barrier(); \
    asm volatile("" ::: "memory"); \
} while (0)

// Load one float4 of weights as two packed f2 pairs, pinned in the reg file.
#define DECLW4(nm, src) \
    float4 _t_##nm = (src); \
    f2 nm##_a = {_t_##nm.x, _t_##nm.y}; \
    f2 nm##_b = {_t_##nm.z, _t_##nm.w}; \
    asm volatile("" : "+v"(nm##_a), "+v"(nm##_b));

// Gate-aligned weight residency: thread (rg,p) holds rows {rg,rg+128,rg+256,rg+384},
// k-slice [32p, 32p+32) -> 128 floats/thread as 64 f2 pairs.
#define LOADW_ALL(W) \
    const float4* wpa_ = (const float4*)((W) + (size_t)(rg)       * H + p * 32); \
    const float4* wpb_ = (const float4*)((W) + (size_t)(rg + 128) * H + p * 32); \
    const float4* wpc_ = (const float4*)((W) + (size_t)(rg + 256) * H + p * 32); \
    const float4* wpd_ = (const float4*)((W) + (size_t)(rg + 384) * H + p * 32); \
    DECLW4(wa0, wpa_[0]) DECLW4(wa1, wpa_[1]) DECLW4(wa2, wpa_[2]) DECLW4(wa3, wpa_[3]) \
    DECLW4(wa4, wpa_[4]) DECLW4(wa5, wpa_[5]) DECLW4(wa6, wpa_[6]) DECLW4(wa7, wpa_[7]) \
    DECLW4(wb0, wpb_[0]) DECLW4(wb1, wpb_[1]) DECLW4(wb2, wpb_[2]) DECLW4(wb3, wpb_[3]) \
    DECLW4(wb4, wpb_[4]) DECLW4(wb5, wpb_[5]) DECLW4(wb6, wpb_[6]) DECLW4(wb7, wpb_[7]) \
    DECLW4(wc0, wpc_[0]) DECLW4(wc1, wpc_[1]) DECLW4(wc2, wpc_[2]) DECLW4(wc3, wpc_[3]) \
    DECLW4(wc4, wpc_[4]) DECLW4(wc5, wpc_[5]) DECLW4(wc6, wpc_[6]) DECLW4(wc7, wpc_[7]) \
    DECLW4(wd0, wpd_[0]) DECLW4(wd1, wpd_[1]) DECLW4(wd2, wpd_[2]) DECLW4(wd3, wpd_[3]) \
    DECLW4(wd4, wpd_[4]) DECLW4(wd5, wpd_[5]) DECLW4(wd6, wpd_[6]) DECLW4(wd7, wpd_[7])

// Packed dual-FMA: acc(lo,hi) += w(lo,hi) * h(lo,hi).
#define PKFMA(acc, w, h) \
    asm("v_pk_fma_f32 %0, %1, %2, %0" : "+v"(acc) : "v"(w), "v"(h));

#define FMA1(nm, hA, hB, acc) PKFMA(acc, nm##_a, hA) PKFMA(acc, nm##_b, hB)

#define DOTJ(j) { \
    f2 hA_ = {hv##j.x, hv##j.y}; f2 hB_ = {hv##j.z, hv##j.w}; \
    FMA1(wa##j, hA_, hB_, q0) FMA1(wb##j, hA_, hB_, q1) \
    FMA1(wc##j, hA_, hB_, q2) FMA1(wd##j, hA_, hB_, q3) }

// 8 b128 broadcast reads + 64 pk_fma + quad reduction -> a0..a3 = full gate dots
#define DOT_BODY(HBASE) \
    const float4* _hp4 = (const float4*)(HBASE); \
    float4 hv0=_hp4[0],hv1=_hp4[1],hv2=_hp4[2],hv3=_hp4[3], \
           hv4=_hp4[4],hv5=_hp4[5],hv6=_hp4[6],hv7=_hp4[7]; \
    f2 q0={0.f,0.f},q1={0.f,0.f},q2={0.f,0.f},q3={0.f,0.f}; \
    DOTJ(0) DOTJ(1) DOTJ(2) DOTJ(3) DOTJ(4) DOTJ(5) DOTJ(6) DOTJ(7) \
    float a0=q0.x+q0.y, a1=q1.x+q1.y, a2=q2.x+q2.y, a3=q3.x+q3.y; \
    a0 = quad_sum(a0); a1 = quad_sum(a1); a2 = quad_sum(a2); a3 = quad_sum(a3);

// ---------------------------------------------------------------------------
// B round: stage clen steps of (h1|v), project through w_ih1, publish flag.
// ---------------------------------------------------------------------------
#define B_ROUND(cstart, clen) { \
    if (r == 0) wait_ge(cntA, (cstart) + (clen)); \
    __syncthreads(); \
    if (r < (clen) * 32) { \
        int tl = r >> 5, k4 = r & 31, s = k4 >> 3, j = k4 & 7; \
        float4 v = *(const float4*)(hsrc + (size_t)((cstart) + tl) * 256 + k4 * 4); \
        *(float4*)&hb[(tl * 4 + s) * 36 + j * 4] = v; \
    } \
    __syncthreads(); \
    _Pragma("unroll") \
    for (int tl = 0; tl < (clen); tl++) { \
        DOT_BODY(hb + (tl * 4 + p) * 36) \
        float sel = (p == 0) ? a0 : (p == 1) ? a1 : (p == 2) ? a2 : a3; \
        pbase[(size_t)((cstart) + tl) * 1024 + r] = sel; \
    } \
    BARRIER_ALL(); \
    if (r == 0) \
        __hip_atomic_store(myCnt, (cstart) + (clen), __ATOMIC_RELEASE, __HIP_MEMORY_SCOPE_AGENT); }

// ---------------------------------------------------------------------------
// C helpers: reduce a finished gbuf buffer (waves 0..plen-1) and scatter its
// diagonals. Used overlapped with the next round's flag spin.
// ---------------------------------------------------------------------------
#define C_REDUCE(pbuf, plen) { \
    const int w_ = r >> 6, l_ = r & 63; \
    if (w_ < (plen)) { \
        float v_ = gbuf[pbuf][w_][l_] + gbuf[pbuf][w_][l_ + 64]; \
        v_ = quad_sum(v_); \
        v_ += __shfl_xor(v_, 4, 64);  v_ += __shfl_xor(v_, 8, 64); \
        v_ += __shfl_xor(v_, 16, 64); v_ += __shfl_xor(v_, 32, 64); \
        if (l_ == 0) scr[w_] = v_; \
    } }

#define C_SCATTER(pstart, plen) \
    if (r < (plen) * 32) { \
        const int tl_ = r >> 5, d_ = r & 31; \
        outp[(size_t)(b * TT + (pstart) + tl_) * 1024 + d_ * 33] = scr[tl_]; \
    }

// C round: spin (lanes 448/449) || reduce prev gbuf; sync; scatter prev;
// prefetch; clen recurrence steps into gbuf[cbuf].
#define C_ROUND(cstart, clen, cbuf, pstart, plen, pbuf, HASPREV) { \
    if (r == 448) wait_ge(cntB1, (cstart) + (clen)); \
    if (r == 449) wait_ge(cntB2, (cstart) + (clen)); \
    if (HASPREV) { C_REDUCE(pbuf, plen) } \
    __syncthreads(); \
    if (HASPREV) { C_SCATTER(pstart, plen) } \
    float4 zf[CH], af[CH]; \
    _Pragma("unroll") \
    for (int tl = 0; tl < (clen); tl++) { \
        zf[tl] = *(const float4*)(parts + (size_t)((cstart) + tl) * 1024 + rg * 4); \
        af[tl] = *(const float4*)(parts + (size_t)((cstart) + tl) * 1024 + 512 + rg * 4); \
    } \
    _Pragma("unroll") \
    for (int tl = 0; tl < (clen); tl++) { \
        const int t = (cstart) + tl; \
        const float* hc = hbuf[t & 1]; \
        float* hx = hbuf[(t & 1) ^ 1]; \
        DOT_BODY(hc + p * 36) \
        float z0 = a0 + b0 + zf[tl].x; \
        float z1 = a1 + b1 + zf[tl].y; \
        float z2 = a2 + b2 + zf[tl].z; \
        float z3 = a3 + b3 + zf[tl].w; \
        float gi = sigf(z0), gf = sigf(z1), gg = tanhf_fast(z2), go = sigf(z3); \
        float di = gi * (1.f - gi) * af[tl].x, df = gf * (1.f - gf) * af[tl].y; \
        float dg = (1.f - gg * gg) * af[tl].z, dd = go * (1.f - go) * af[tl].w; \
        float dc = df * c2 + di * gg + gi * dg; \
        c2 = gf * c2 + gi * gg; \
        float th = tanhf_fast(c2); \
        if (p == wsl) hx[p * 36 + wpos] = go * th; \
        float dh2 = dd * th + go * (1.f - th * th) * dc; \
        if (p == 0) gbuf[cbuf][tl][rg] = wo * dh2; \
        BARRIER_LGKM(); \
    } }

// ---------------------------------------------------------------------------
// Overlapped 4-role pipeline, one CU per (role,batch): 32 blocks x 512 thr.
//   role 0 = A : layer-1 recurrence (w_hh0)        -> h1[t], v[t]
//   role 1 = B1: w_ih1 @ h1 (chunked)              -> parts[.., 0:512)
//   role 2 = B2: w_ih1 @ v  (chunked)              -> parts[.., 512:1024)
//   role 3 = C : w_hh1 @ h2 + elementwise -> DIAGONAL-only output scatter
// Output zeros are pre-written by hipMemsetAsync before this kernel.
// TAPERED TAIL: chunks of 8 for t<120, then 2x4 (flags at 124, 128) — after
// A retires step 127, C has only 4 serial steps left instead of 8.
// ---------------------------------------------------------------------------
__global__ __launch_bounds__(512)
__attribute__((amdgpu_waves_per_eu(1, 2)))
void pipe_kernel(const float* __restrict__ x,
                 const float* __restrict__ w_ih0,
                 const float* __restrict__ w_hh0,
                 const float* __restrict__ b_ih0,
                 const float* __restrict__ b_hh0,
                 const float* __restrict__ w_ih1,
                 const float* __restrict__ w_hh1,
                 const float* __restrict__ b_ih1,
                 const float* __restrict__ b_hh1,
                 const float* __restrict__ w_out,
                 float* __restrict__ ws,
                 float* __restrict__ outp) {
    const int role = blockIdx.x >> 3;
    const int b    = blockIdx.x & 7;
    const int r    = threadIdx.x;
    const int rg   = r >> 2, p = r & 3;
    const int wsl  = rg >> 5, wpos = rg & 31;

    int* cntA  = (int*)ws + OFF_CNT       + b * 32;
    int* cntB1 = (int*)ws + OFF_CNT + 256 + b * 32;
    int* cntB2 = (int*)ws + OFF_CNT + 512 + b * 32;
    float* h1v = ws + OFF_H1V + (size_t)b * TT * 256;

    __shared__ float hbuf[2][144];    // recurrent state, 4 padded slices x 36
    __shared__ float u_s[TT];
    __shared__ float scr[512];
    __shared__ float hb[CH * 144];    // B chunk staging
    __shared__ float gbuf[2][CH][128]; // C: double-buffered unreduced g

    if (role == 0) {
        // ===================== Stage A: layer-1 recurrence =====================
        LOADW_ALL(w_hh0)
        const float b0 = b_ih0[rg]       + b_hh0[rg];
        const float b1 = b_ih0[rg + 128] + b_hh0[rg + 128];
        const float b2 = b_ih0[rg + 256] + b_hh0[rg + 256];
        const float b3 = b_ih0[rg + 384] + b_hh0[rg + 384];
        const float wi0 = w_ih0[rg], wi1 = w_ih0[rg + 128];
        const float wi2 = w_ih0[rg + 256], wi3 = w_ih0[rg + 384];
        {   // u[t] = trace(x[b,t]) cooperatively (4 partials per t)
            const float* xb = x + (size_t)(b * TT + (r & 127)) * 1024;
            const int pq = r >> 7;
            float u = 0.f;
#pragma unroll
            for (int i = 0; i < 8; i++) u += xb[(pq * 8 + i) * 33];
            scr[r] = u;
        }
        if (r < 144) hbuf[0][r] = 0.f;
        __syncthreads();
        if (r < TT) u_s[r] = scr[r] + scr[r + 128] + scr[r + 256] + scr[r + 384];
        __syncthreads();

        float c1 = 0.f;
        float hn_prev = 0.f, vn_prev = 0.f;
        for (int t = 0; t < TT; t++) {
            // publish PREVIOUS step's h1v (retires in this step's shadow)
            if (t > 0) {
                if (p == 0) h1v[(t - 1) * 256 + rg] = hn_prev;
                if (p == 1) h1v[(t - 1) * 256 + 128 + rg] = vn_prev;
            }
            const float u = u_s[t];
            const float* hc = hbuf[t & 1];
            float* hx = hbuf[(t & 1) ^ 1];
            DOT_BODY(hc + p * 36)
            float z0 = a0 + fmaf(wi0, u, b0);
            float z1 = a1 + fmaf(wi1, u, b1);
            float z2 = a2 + fmaf(wi2, u, b2);
            float z3 = a3 + fmaf(wi3, u, b3);
            float gi = sigf(z0), gf = sigf(z1), gg = tanhf_fast(z2), go = sigf(z3);
            float di = gi * (1.f - gi) * wi0, df = gf * (1.f - gf) * wi1;
            float dg = (1.f - gg * gg) * wi2, dd = go * (1.f - go) * wi3;
            float dc = df * c1 + di * gg + gi * dg;
            c1 = gf * c1 + gi * gg;
            float th = tanhf_fast(c1);
            float hn = go * th;
            float vn = dd * th + go * (1.f - th * th) * dc;
            if (p == wsl) hx[p * 36 + wpos] = hn;       // one writer per h-index
            hn_prev = hn; vn_prev = vn;
            if (t > 0 && ((t & (CH - 1)) == 0 || t == 124)) {
                // deferred flag: the prior chunk's last store was issued at
                // the TOP of this step -> vmcnt(0) here is ~free.
                BARRIER_ALL();
                if (r == 0)
                    __hip_atomic_store(cntA, t, __ATOMIC_RELEASE, __HIP_MEMORY_SCOPE_AGENT);
            } else {
                BARRIER_LGKM();  // LDS recurrence state only — no vmcnt drain
            }
        }
        // epilogue: publish final step, drain, release final flag
        if (p == 0) h1v[(TT - 1) * 256 + rg] = hn_prev;
        if (p == 1) h1v[(TT - 1) * 256 + 128 + rg] = vn_prev;
        BARRIER_ALL();
        if (r == 0)
            __hip_atomic_store(cntA, TT, __ATOMIC_RELEASE, __HIP_MEMORY_SCOPE_AGENT);
    } else if (role == 1 || role == 2) {
        // ============ Stages B1/B2: w_ih1 @ (h1 | v), chunk-parallel ============
        LOADW_ALL(w_ih1)
        int* myCnt = (role == 2) ? cntB2 : cntB1;
        const float* hsrc = h1v + ((role == 2) ? 128 : 0);
        float* pbase = ws + OFF_PARTS + (size_t)b * TT * 1024 + ((role == 2) ? 512 : 0);
        for (int c = 0; c < 15; c++) { B_ROUND(c * CH, CH) }
        B_ROUND(120, 4)
        B_ROUND(124, 4)
    } else {
        // ==== Stage C: w_hh1 @ h2 + layer-2 elementwise + diag-only scatter ====
        LOADW_ALL(w_hh1)
        const float b0 = b_ih1[rg]       + b_hh1[rg];
        const float b1 = b_ih1[rg + 128] + b_hh1[rg + 128];
        const float b2 = b_ih1[rg + 256] + b_hh1[rg + 256];
        const float b3 = b_ih1[rg + 384] + b_hh1[rg + 384];
        const float wo = w_out[rg];
        if (r < 144) hbuf[0][r] = 0.f;
        __syncthreads();
        const float* parts = ws + OFF_PARTS + (size_t)b * TT * 1024;
        float c2 = 0.f;
        // round 0 (no prev)
        C_ROUND(0, CH, 0, 0, 0, 0, 0)
        // rounds 1..14 (prev = round c-1, len 8)
        for (int c = 1; c < 15; c++) {
            C_ROUND(c * CH, CH, c & 1, (c - 1) * CH, CH, (c - 1) & 1, 1)
        }
        // round 15: steps 120-123 (prev = round 14, buf 0)
        C_ROUND(120, 4, 1, 112, CH, 0, 1)
        // round 16: steps 124-127 (prev = round 15, buf 1)
        C_ROUND(124, 4, 0, 120, 4, 1, 1)
        // final: reduce + scatter round 16 (buf 0, len 4)
        {
            C_REDUCE(0, 4)
            BARRIER_LGKM();
            C_SCATTER(124, 4)
        }
    }
}

extern "C" void kernel_launch(void* const* d_in, const int* in_sizes, int n_in,
                              void* d_out, int out_size, void* d_ws, size_t ws_size,
                              hipStream_t stream) {
    const float* x     = (const float*)d_in[0];
    const float* w_ih0 = (const float*)d_in[1];
    const float* w_hh0 = (const float*)d_in[2];
    const float* b_ih0 = (const float*)d_in[3];
    const float* b_hh0 = (const float*)d_in[4];
    const float* w_ih1 = (const float*)d_in[5];
    const float* w_hh1 = (const float*)d_in[6];
    const float* b_ih1 = (const float*)d_in[7];
    const float* b_hh1 = (const float*)d_in[8];
    const float* w_out = (const float*)d_in[9];
    // d_in[10] = b_out: constant offset, zero derivative -> unused

    float* ws = (float*)d_ws;   // counters rely on 0xAA poison (<0 as int)

    // Zero the output (31/32 of it stays zero; pipe_kernel scatters diagonals).
    hipMemsetAsync(d_out, 0, (size_t)out_size, stream);

    pipe_kernel<<<dim3(32), dim3(512), 0, stream>>>(x, w_ih0, w_hh0, b_ih0, b_hh0,
                                                    w_ih1, w_hh1, b_ih1, b_hh1, w_out,
                                                    ws, (float*)d_out);
}